// Round 2
// baseline (3994.857 us; speedup 1.0000x reference)
//
#include <hip/hip_runtime.h>
#include <hip/hip_bf16.h>

typedef __hip_bfloat16 bf16;

// Problem constants (fixed by reference):
// B=4, H=W=60, C=256, HEADS=8, hd=32, WS=7, pad=3 -> 9x9 windows/batch,
// 324 windows total, 49 q-tokens/window, key window 27x27=729 from 27x27 grid,
// left pad 12, NEG=-1000.
// ALL inputs/outputs are FLOAT32 (reference is jnp.float32). Internal staging
// buffers are bf16 (threshold = 2% of max|ref| tolerates it).

__device__ __forceinline__ float u2f(unsigned short u){
  union { unsigned int i; float f; } c; c.i = ((unsigned int)u) << 16; return c.f;
}
__device__ __forceinline__ float2 up2f(unsigned int u){
  union { unsigned int i; float f; } a, b;
  a.i = u << 16; b.i = u & 0xffff0000u;
  return make_float2(a.f, b.f);
}
__device__ __forceinline__ bf16 f2bf(float f){ return __float2bfloat16(f); }

// ---------------- K1: LN(y) + kv projection (valid 27x27 grid only) --------
// grid = 729 blocks (4 tokens each), 256 threads. kvbuf[b*729+s][0:512] bf16.
__global__ __launch_bounds__(256) void kv_kernel(
    const float* __restrict__ y, const float* __restrict__ g,
    const float* __restrict__ bb, const float* __restrict__ kv_w,
    bf16* __restrict__ kvbuf){
  __shared__ __align__(16) float xn[4*256];
  int tid = threadIdx.x, wid = tid >> 6, lane = tid & 63;
  int bs0 = blockIdx.x * 4;
  {
    int bs = bs0 + wid;  // wave per token
    float4 v = ((const float4*)(y + (size_t)bs*256))[lane];
    float s = v.x+v.y+v.z+v.w, ss = v.x*v.x+v.y*v.y+v.z*v.z+v.w*v.w;
    #pragma unroll
    for (int off=32; off; off>>=1){ s += __shfl_xor(s,off); ss += __shfl_xor(ss,off); }
    float mean = s*(1.f/256.f);
    float var  = fmaxf(ss*(1.f/256.f) - mean*mean, 0.f);
    float inv  = rsqrtf(var + 1e-5f);
    float4 g4 = ((const float4*)g)[lane];
    float4 b4 = ((const float4*)bb)[lane];
    float4 o;
    o.x=(v.x-mean)*inv*g4.x+b4.x;
    o.y=(v.y-mean)*inv*g4.y+b4.y;
    o.z=(v.z-mean)*inv*g4.z+b4.z;
    o.w=(v.w-mean)*inv*g4.w+b4.w;
    ((float4*)xn)[wid*64 + lane] = o;
  }
  __syncthreads();
  float acc[4][2];
  #pragma unroll
  for (int t=0;t<4;t++){ acc[t][0]=0.f; acc[t][1]=0.f; }
  for (int k4=0;k4<64;k4++){
    float xv[4][4];
    #pragma unroll
    for (int t=0;t<4;t++) *(float4*)&xv[t][0] = ((const float4*)xn)[t*64+k4];
    #pragma unroll
    for (int j=0;j<4;j++){
      int k = k4*4+j;
      float w0 = kv_w[(size_t)k*512 + tid];
      float w1 = kv_w[(size_t)k*512 + 256 + tid];
      #pragma unroll
      for (int t=0;t<4;t++){
        acc[t][0] = fmaf(xv[t][j], w0, acc[t][0]);
        acc[t][1] = fmaf(xv[t][j], w1, acc[t][1]);
      }
    }
  }
  #pragma unroll
  for (int t=0;t<4;t++){
    kvbuf[(size_t)(bs0+t)*512 + tid]       = f2bf(acc[t][0]);
    kvbuf[(size_t)(bs0+t)*512 + 256 + tid] = f2bf(acc[t][1]);
  }
}

// ---------------- K2: per-window LN(xw) + q projection ---------------------
// grid = 324 blocks, 256 threads. qbuf[w][t][256] bf16.
__global__ __launch_bounds__(256) void q_kernel(
    const float* __restrict__ x, const float* __restrict__ g,
    const float* __restrict__ bb, const float* __restrict__ q_w,
    bf16* __restrict__ qbuf){
  __shared__ __align__(16) float xn[49*256];
  int tid = threadIdx.x, wid = tid>>6, lane = tid&63;
  int w = blockIdx.x;
  int b = w/81, wi = w - b*81, wh = wi/9, ww = wi - wh*9;
  float4 g4 = ((const float4*)g)[lane];
  float4 b4 = ((const float4*)bb)[lane];
  for (int t=wid; t<49; t+=4){
    int r = t/7, c = t - r*7;
    int gh = wh*7 + r, gw = ww*7 + c;
    float4 v = make_float4(0.f,0.f,0.f,0.f);
    if (gh < 60 && gw < 60){
      v = ((const float4*)(x + (size_t)(b*3600 + gh*60 + gw)*256))[lane];
    }
    float s=v.x+v.y+v.z+v.w, ss=v.x*v.x+v.y*v.y+v.z*v.z+v.w*v.w;
    #pragma unroll
    for (int off=32; off; off>>=1){ s += __shfl_xor(s,off); ss += __shfl_xor(ss,off); }
    float mean = s*(1.f/256.f);
    float var = fmaxf(ss*(1.f/256.f)-mean*mean, 0.f);
    float inv = rsqrtf(var+1e-5f);
    float4 o;
    o.x=(v.x-mean)*inv*g4.x+b4.x;
    o.y=(v.y-mean)*inv*g4.y+b4.y;
    o.z=(v.z-mean)*inv*g4.z+b4.z;
    o.w=(v.w-mean)*inv*g4.w+b4.w;
    ((float4*)xn)[t*64 + lane] = o;
  }
  __syncthreads();
  float acc[49];
  #pragma unroll
  for (int t=0;t<49;t++) acc[t]=0.f;
  for (int k4=0;k4<64;k4++){
    float wv[4];
    #pragma unroll
    for (int j=0;j<4;j++) wv[j] = q_w[(size_t)(k4*4+j)*256 + tid];
    #pragma unroll
    for (int t=0;t<49;t++){
      float xv[4];
      *(float4*)xv = ((const float4*)xn)[t*64+k4];
      acc[t] = fmaf(xv[0],wv[0],fmaf(xv[1],wv[1],fmaf(xv[2],wv[2],fmaf(xv[3],wv[3],acc[t]))));
    }
  }
  bf16* qb = qbuf + (size_t)w*49*256 + tid;
  #pragma unroll
  for (int t=0;t<49;t++) qb[t*256] = f2bf(acc[t]);
}

// ---------------- K3: windowed attention, one block per (window, head) -----
// grid = 324*8, 256 threads (4 waves; wave handles queries t, t+4, ...).
// k/v head-slices staged in LDS, stride 34 bf16 (dword-aligned, conflict-free).
__global__ __launch_bounds__(256) void attn_kernel(
    const bf16* __restrict__ qbuf, const bf16* __restrict__ kvbuf,
    bf16* __restrict__ obuf){
  __shared__ __align__(16) bf16 kls[729*34];
  __shared__ __align__(16) bf16 vls[729*34];
  int tid = threadIdx.x, wid = tid>>6, lane = tid&63;
  int blk = blockIdx.x;
  int w = blk >> 3, hh = blk & 7;
  int b = w/81, wi = w - b*81, wh = wi/9, ww = wi - wh*9;
  const bf16* kvb = kvbuf + (size_t)b*729*512 + hh*32;
  // stage: 729 keys x 16 dwords (32 bf16) for k and v
  for (int idx = tid; idx < 729*16; idx += 256){
    int kk = idx >> 4, dw = idx & 15;
    int kr = kk/27, kc = kk - kr*27;
    int gr = wh*3 + kr - 12, gc = ww*3 + kc - 12;
    unsigned int kd = 0u, vd = 0u;
    if ((unsigned)gr < 27u && (unsigned)gc < 27u){
      const unsigned int* sp = (const unsigned int*)(kvb + (size_t)(gr*27+gc)*512);
      kd = sp[dw];
      vd = sp[128 + dw];
    }
    *(unsigned int*)&kls[kk*34 + dw*2] = kd;
    *(unsigned int*)&vls[kk*34 + dw*2] = vd;
  }
  __syncthreads();
  for (int t = wid; t < 49; t += 4){
    // load q row (32 dims) into regs
    const unsigned int* qp = (const unsigned int*)(qbuf + ((size_t)w*49 + t)*256 + hh*32);
    float qv[32];
    #pragma unroll
    for (int i=0;i<16;i++){ float2 f = up2f(qp[i]); qv[2*i]=f.x; qv[2*i+1]=f.y; }
    // scores: lane owns keys ch*64+lane
    float s[12];
    #pragma unroll
    for (int ch=0; ch<12; ch++){
      int kk = ch*64 + lane;
      float val = -30000.f;
      if (kk < 729){
        const unsigned int* kp = (const unsigned int*)&kls[kk*34];
        float acc = 0.f;
        #pragma unroll
        for (int i=0;i<16;i++){
          float2 kf = up2f(kp[i]);
          acc = fmaf(qv[2*i], kf.x, acc);
          acc = fmaf(qv[2*i+1], kf.y, acc);
        }
        int kr = kk/27, kc = kk - kr*27;
        int gr = wh*3 + kr - 12, gc = ww*3 + kc - 12;
        bool bad = ((unsigned)gr >= 27u) || ((unsigned)gc >= 27u) || (gr >= 24 && gc >= 24);
        val = acc * 0.17677669529663689f + (bad ? -1000.f : 0.f);
      }
      s[ch] = val;
    }
    float m = s[0];
    #pragma unroll
    for (int ch=1; ch<12; ch++) m = fmaxf(m, s[ch]);
    #pragma unroll
    for (int off=32; off; off>>=1) m = fmaxf(m, __shfl_xor(m, off));
    float p[12];
    float l = 0.f;
    #pragma unroll
    for (int ch=0; ch<12; ch++){ p[ch] = __expf(s[ch]-m); l += p[ch]; }
    #pragma unroll
    for (int off=32; off; off>>=1) l += __shfl_xor(l, off);
    float rl = 1.f / l;
    float o[32];
    #pragma unroll
    for (int d=0; d<32; d++) o[d]=0.f;
    #pragma unroll
    for (int ch=0; ch<12; ch++){
      int kk = ch*64 + lane;
      if (kk < 729){
        const unsigned int* vp = (const unsigned int*)&vls[kk*34];
        float pc = p[ch];
        #pragma unroll
        for (int i=0;i<16;i++){
          float2 vf = up2f(vp[i]);
          o[2*i]   = fmaf(pc, vf.x, o[2*i]);
          o[2*i+1] = fmaf(pc, vf.y, o[2*i+1]);
        }
      }
    }
    #pragma unroll
    for (int off=32; off; off>>=1){
      #pragma unroll
      for (int d=0; d<32; d++) o[d] += __shfl_xor(o[d], off);
    }
    if (lane == 0){
      bf16* op = obuf + ((size_t)w*49 + t)*256 + hh*32;
      #pragma unroll
      for (int d=0; d<32; d++) op[d] = f2bf(o[d]*rl);
    }
  }
}

// ---------------- K4: out-proj + shortcut + ls1, window-reverse + crop -----
// grid = 324 blocks, 256 threads. writes xobuf (f32, B*3600*256).
__global__ __launch_bounds__(256) void proj_kernel(
    const bf16* __restrict__ obuf, const float* __restrict__ x,
    const float* __restrict__ proj_w, const float* __restrict__ proj_b,
    const float* __restrict__ ls1, float* __restrict__ xobuf){
  __shared__ __align__(16) float ol[49*256];
  int tid = threadIdx.x;
  int w = blockIdx.x;
  int b = w/81, wi = w - b*81, wh = wi/9, ww = wi - wh*9;
  for (int idx=tid; idx<49*64; idx+=256){
    ushort4 raw = ((const ushort4*)(obuf + (size_t)w*49*256))[idx];
    float4 o; o.x=u2f(raw.x); o.y=u2f(raw.y); o.z=u2f(raw.z); o.w=u2f(raw.w);
    ((float4*)ol)[idx] = o;
  }
  __syncthreads();
  float acc[49];
  #pragma unroll
  for (int t=0;t<49;t++) acc[t]=0.f;
  for (int k4=0;k4<64;k4++){
    float wv[4];
    #pragma unroll
    for (int j=0;j<4;j++) wv[j] = proj_w[(size_t)(k4*4+j)*256 + tid];
    #pragma unroll
    for (int t=0;t<49;t++){
      float xv[4];
      *(float4*)xv = ((const float4*)ol)[t*64+k4];
      acc[t] = fmaf(xv[0],wv[0],fmaf(xv[1],wv[1],fmaf(xv[2],wv[2],fmaf(xv[3],wv[3],acc[t]))));
    }
  }
  float pb = proj_b[tid];
  float l1 = ls1[tid];
  #pragma unroll
  for (int t=0;t<49;t++){
    int r=t/7, c=t-r*7;
    int gh=wh*7+r, gw=ww*7+c;
    if (gh<60 && gw<60){
      size_t p = (size_t)(b*3600 + gh*60 + gw)*256 + tid;
      float sc = x[p];
      xobuf[p] = sc + l1*(acc[t]+pb);
    }
  }
}

// ---------------- K5: LN + fc1 + GELU(erf) + fc2 + residual ----------------
// grid = 1800 blocks (8 tokens each), 256 threads.
__global__ __launch_bounds__(256) void mlp_kernel(
    const float* __restrict__ xobuf, const float* __restrict__ g,
    const float* __restrict__ bb, const float* __restrict__ fc1_w,
    const float* __restrict__ fc1_b, const float* __restrict__ fc2_w,
    const float* __restrict__ fc2_b, const float* __restrict__ ls2,
    float* __restrict__ out){
  __shared__ __align__(16) float xn[8*256];
  __shared__ __align__(16) float h1[8*1024];
  int tid = threadIdx.x, wid = tid>>6, lane = tid&63;
  int tok0 = blockIdx.x * 8;
  float4 g4 = ((const float4*)g)[lane];
  float4 b4 = ((const float4*)bb)[lane];
  #pragma unroll
  for (int tt=0; tt<2; tt++){
    int t = wid*2 + tt;
    float4 v = ((const float4*)(xobuf + (size_t)(tok0+t)*256))[lane];
    float s = v.x+v.y+v.z+v.w;
    float ss = v.x*v.x+v.y*v.y+v.z*v.z+v.w*v.w;
    #pragma unroll
    for (int off=32; off; off>>=1){ s += __shfl_xor(s,off); ss += __shfl_xor(ss,off); }
    float mean = s*(1.f/256.f);
    float var = fmaxf(ss*(1.f/256.f)-mean*mean, 0.f);
    float inv = rsqrtf(var+1e-5f);
    float4 o;
    o.x=(v.x-mean)*inv*g4.x+b4.x;
    o.y=(v.y-mean)*inv*g4.y+b4.y;
    o.z=(v.z-mean)*inv*g4.z+b4.z;
    o.w=(v.w-mean)*inv*g4.w+b4.w;
    ((float4*)xn)[t*64 + lane] = o;
  }
  __syncthreads();
  // fc1: thread -> cols {tid, tid+256, tid+512, tid+768} x 8 tokens
  float acc[8][4];
  #pragma unroll
  for (int t=0;t<8;t++){
    #pragma unroll
    for (int c=0;c<4;c++) acc[t][c]=0.f;
  }
  for (int k4=0;k4<64;k4++){
    float xv[8][4];
    #pragma unroll
    for (int t=0;t<8;t++) *(float4*)&xv[t][0] = ((const float4*)xn)[t*64+k4];
    #pragma unroll
    for (int j=0;j<4;j++){
      int k = k4*4+j;
      const float* wr = fc1_w + (size_t)k*1024 + tid;
      float w0=wr[0], w1=wr[256], w2=wr[512], w3=wr[768];
      #pragma unroll
      for (int t=0;t<8;t++){
        float xvj = xv[t][j];
        acc[t][0]=fmaf(xvj,w0,acc[t][0]);
        acc[t][1]=fmaf(xvj,w1,acc[t][1]);
        acc[t][2]=fmaf(xvj,w2,acc[t][2]);
        acc[t][3]=fmaf(xvj,w3,acc[t][3]);
      }
    }
  }
  float fb[4];
  #pragma unroll
  for (int c=0;c<4;c++) fb[c] = fc1_b[tid + c*256];
  #pragma unroll
  for (int t=0;t<8;t++){
    #pragma unroll
    for (int c=0;c<4;c++){
      float h = acc[t][c] + fb[c];
      h = 0.5f*h*(1.f + erff(h*0.70710678118654752f));
      h1[t*1024 + tid + c*256] = h;
    }
  }
  __syncthreads();
  // fc2: thread -> col tid x 8 tokens
  float a2[8];
  #pragma unroll
  for (int t=0;t<8;t++) a2[t]=0.f;
  for (int k4=0;k4<256;k4++){
    float hv[8][4];
    #pragma unroll
    for (int t=0;t<8;t++) *(float4*)&hv[t][0] = ((const float4*)h1)[t*256+k4];
    #pragma unroll
    for (int j=0;j<4;j++){
      int k = k4*4+j;
      float wv = fc2_w[(size_t)k*256 + tid];
      #pragma unroll
      for (int t=0;t<8;t++) a2[t] = fmaf(hv[t][j], wv, a2[t]);
    }
  }
  float c2 = fc2_b[tid];
  float l2 = ls2[tid];
  #pragma unroll
  for (int t=0;t<8;t++){
    size_t p = (size_t)(tok0+t)*256 + tid;
    out[p] = xobuf[p] + l2*(a2[t]+c2);
  }
}

extern "C" void kernel_launch(void* const* d_in, const int* in_sizes, int n_in,
                              void* d_out, int out_size, void* d_ws, size_t ws_size,
                              hipStream_t stream) {
  (void)in_sizes; (void)n_in; (void)out_size; (void)ws_size;
  const float* x      = (const float*)d_in[0];
  const float* y      = (const float*)d_in[1];
  const float* n1g    = (const float*)d_in[2];
  const float* n1b    = (const float*)d_in[3];
  const float* q_w    = (const float*)d_in[4];
  const float* kv_w   = (const float*)d_in[5];
  const float* proj_w = (const float*)d_in[6];
  const float* proj_b = (const float*)d_in[7];
  const float* n2g    = (const float*)d_in[8];
  const float* n2b    = (const float*)d_in[9];
  const float* fc1_w  = (const float*)d_in[10];
  const float* fc1_b  = (const float*)d_in[11];
  const float* fc2_w  = (const float*)d_in[12];
  const float* fc2_b  = (const float*)d_in[13];
  const float* ls1    = (const float*)d_in[14];
  const float* ls2    = (const float*)d_in[15];

  char* ws = (char*)d_ws;
  // Time-disjoint layout (22.9 MB total):
  //   kvbuf bf16[4*729*512]   @ 0          (2,985,984 B)   live K1..K3
  //   qbuf  bf16[324*49*256]  @ 2,985,984  (8,128,512 B)   live K2..K3
  //   obuf  bf16[324*49*256]  @ 14,745,600 (8,128,512 B)   live K3..K4
  //   xobuf f32 [4*3600*256]  @ 0          (14,745,600 B)  live K4..K5 (overlays dead kv/q)
  bf16*  kvbuf = (bf16*)(ws);
  bf16*  qbuf  = (bf16*)(ws + 2985984);
  bf16*  obuf  = (bf16*)(ws + 14745600);
  float* xobuf = (float*)(ws);

  kv_kernel<<<729, 256, 0, stream>>>(y, n1g, n1b, kv_w, kvbuf);
  q_kernel<<<324, 256, 0, stream>>>(x, n1g, n1b, q_w, qbuf);
  attn_kernel<<<2592, 256, 0, stream>>>(qbuf, kvbuf, obuf);
  proj_kernel<<<324, 256, 0, stream>>>(obuf, x, proj_w, proj_b, ls1, xobuf);
  mlp_kernel<<<1800, 256, 0, stream>>>(xobuf, n2g, n2b, fc1_w, fc1_b, fc2_w, fc2_b, ls2,
                                       (float*)d_out);
}

// Round 3
// 609.878 us; speedup vs baseline: 6.5503x; 6.5503x over previous
//
#include <hip/hip_runtime.h>
#include <hip/hip_bf16.h>

typedef __hip_bfloat16 bf16;
typedef __attribute__((ext_vector_type(8))) short bf16x8;
typedef __attribute__((ext_vector_type(4))) float f32x4;

// Problem constants: B=4, H=W=60, C=256, HEADS=8, hd=32, WS=7 -> 9x9 windows/batch,
// 324 windows, 49 q/window, key window 27x27=729 gathered from 27x27 grid (stride 3,
// offset -12), corner mask (gr>=24 && gc>=24), NEG=-1000 (==0 weight in f32 softmax).
// All external I/O f32; staging buffers bf16.

__device__ __forceinline__ bf16 f2bf(float f){ return __float2bfloat16(f); }
__device__ __forceinline__ unsigned short f2bfu(float f){
  __hip_bfloat16 h = __float2bfloat16(f);
  return *(unsigned short*)&h;
}

// ---------------- K1: LN(y) + kv projection (valid 27x27 grid only) --------
__global__ __launch_bounds__(256) void kv_kernel(
    const float* __restrict__ y, const float* __restrict__ g,
    const float* __restrict__ bb, const float* __restrict__ kv_w,
    bf16* __restrict__ kvbuf){
  __shared__ __align__(16) float xn[4*256];
  int tid = threadIdx.x, wid = tid >> 6, lane = tid & 63;
  int bs0 = blockIdx.x * 4;
  {
    int bs = bs0 + wid;
    float4 v = ((const float4*)(y + (size_t)bs*256))[lane];
    float s = v.x+v.y+v.z+v.w, ss = v.x*v.x+v.y*v.y+v.z*v.z+v.w*v.w;
    #pragma unroll
    for (int off=32; off; off>>=1){ s += __shfl_xor(s,off); ss += __shfl_xor(ss,off); }
    float mean = s*(1.f/256.f);
    float var  = fmaxf(ss*(1.f/256.f) - mean*mean, 0.f);
    float inv  = rsqrtf(var + 1e-5f);
    float4 g4 = ((const float4*)g)[lane];
    float4 b4 = ((const float4*)bb)[lane];
    float4 o;
    o.x=(v.x-mean)*inv*g4.x+b4.x;
    o.y=(v.y-mean)*inv*g4.y+b4.y;
    o.z=(v.z-mean)*inv*g4.z+b4.z;
    o.w=(v.w-mean)*inv*g4.w+b4.w;
    ((float4*)xn)[wid*64 + lane] = o;
  }
  __syncthreads();
  float acc[4][2];
  #pragma unroll
  for (int t=0;t<4;t++){ acc[t][0]=0.f; acc[t][1]=0.f; }
  for (int k4=0;k4<64;k4++){
    float xv[4][4];
    #pragma unroll
    for (int t=0;t<4;t++) *(float4*)&xv[t][0] = ((const float4*)xn)[t*64+k4];
    #pragma unroll
    for (int j=0;j<4;j++){
      int k = k4*4+j;
      float w0 = kv_w[(size_t)k*512 + tid];
      float w1 = kv_w[(size_t)k*512 + 256 + tid];
      #pragma unroll
      for (int t=0;t<4;t++){
        acc[t][0] = fmaf(xv[t][j], w0, acc[t][0]);
        acc[t][1] = fmaf(xv[t][j], w1, acc[t][1]);
      }
    }
  }
  #pragma unroll
  for (int t=0;t<4;t++){
    kvbuf[(size_t)(bs0+t)*512 + tid]       = f2bf(acc[t][0]);
    kvbuf[(size_t)(bs0+t)*512 + 256 + tid] = f2bf(acc[t][1]);
  }
}

// ---------------- K2: per-window LN(xw) + q projection (scale folded) ------
__global__ __launch_bounds__(256) void q_kernel(
    const float* __restrict__ x, const float* __restrict__ g,
    const float* __restrict__ bb, const float* __restrict__ q_w,
    bf16* __restrict__ qbuf){
  __shared__ __align__(16) float xn[49*256];
  int tid = threadIdx.x, wid = tid>>6, lane = tid&63;
  int w = blockIdx.x;
  int b = w/81, wi = w - b*81, wh = wi/9, ww = wi - wh*9;
  float4 g4 = ((const float4*)g)[lane];
  float4 b4 = ((const float4*)bb)[lane];
  for (int t=wid; t<49; t+=4){
    int r = t/7, c = t - r*7;
    int gh = wh*7 + r, gw = ww*7 + c;
    float4 v = make_float4(0.f,0.f,0.f,0.f);
    if (gh < 60 && gw < 60){
      v = ((const float4*)(x + (size_t)(b*3600 + gh*60 + gw)*256))[lane];
    }
    float s=v.x+v.y+v.z+v.w, ss=v.x*v.x+v.y*v.y+v.z*v.z+v.w*v.w;
    #pragma unroll
    for (int off=32; off; off>>=1){ s += __shfl_xor(s,off); ss += __shfl_xor(ss,off); }
    float mean = s*(1.f/256.f);
    float var = fmaxf(ss*(1.f/256.f)-mean*mean, 0.f);
    float inv = rsqrtf(var+1e-5f);
    float4 o;
    o.x=(v.x-mean)*inv*g4.x+b4.x;
    o.y=(v.y-mean)*inv*g4.y+b4.y;
    o.z=(v.z-mean)*inv*g4.z+b4.z;
    o.w=(v.w-mean)*inv*g4.w+b4.w;
    ((float4*)xn)[t*64 + lane] = o;
  }
  __syncthreads();
  float acc[49];
  #pragma unroll
  for (int t=0;t<49;t++) acc[t]=0.f;
  for (int k4=0;k4<64;k4++){
    float wv[4];
    #pragma unroll
    for (int j=0;j<4;j++) wv[j] = q_w[(size_t)(k4*4+j)*256 + tid];
    #pragma unroll
    for (int t=0;t<49;t++){
      float xv[4];
      *(float4*)xv = ((const float4*)xn)[t*64+k4];
      acc[t] = fmaf(xv[0],wv[0],fmaf(xv[1],wv[1],fmaf(xv[2],wv[2],fmaf(xv[3],wv[3],acc[t]))));
    }
  }
  bf16* qb = qbuf + (size_t)w*49*256 + tid;
  #pragma unroll
  for (int t=0;t<49;t++) qb[t*256] = f2bf(acc[t]*0.17677669529663689f); // hd^-0.5 folded
}

// ---------------- K3: flash-style MFMA attention ---------------------------
// block = (window, head): grid 324*8, 256 threads = 4 waves x 16 q-rows.
// Keys tiled 128 (6 tiles over 768 padded). LDS ~33.8 KB -> 4 blocks/CU.
__global__ __launch_bounds__(256) void attn_kernel(
    const bf16* __restrict__ qbuf, const bf16* __restrict__ kvbuf,
    bf16* __restrict__ obuf){
  __shared__ __align__(16) unsigned short Kls[4*128*8];   // [g][key][e] 8 KB
  __shared__ __align__(16) unsigned short Vls[128*34];    // [key][d] pad-34, 8.5 KB
  __shared__ __align__(16) float maskls[128];
  __shared__ __align__(16) unsigned short Pls[4][16*128]; // per-wave P, swizzled, 16 KB

  int tid = threadIdx.x, wid = tid>>6, lane = tid&63;
  int g = lane>>4, li = lane&15;
  int blk = blockIdx.x;
  int w = blk >> 3, hh = blk & 7;
  int b = w/81, wi = w - b*81, wh = wi/9, ww = wi - wh*9;
  const bf16* kvb = kvbuf + (size_t)b*729*512 + hh*32;

  // Q A-fragment: row = li (q), k-slot = g*8+e  (held in regs whole kernel)
  bf16x8 qa;
  #pragma unroll
  for (int e=0;e<8;e++) qa[e]=0;
  int qrow = wid*16 + li;
  if (qrow < 49){
    qa = *(const bf16x8*)(qbuf + ((size_t)w*49+qrow)*256 + hh*32 + g*8);
  }

  f32x4 o0 = {0.f,0.f,0.f,0.f}, o1 = {0.f,0.f,0.f,0.f};
  float mrow[4], lrow[4];
  #pragma unroll
  for (int r=0;r<4;r++){ mrow[r] = -3.0e38f; lrow[r] = 0.f; }

  for (int tile=0; tile<6; tile++){
    int kbase = tile*128;
    // ---- stage K, V, mask (512 items: g=item&3, key=item>>2) ----
    #pragma unroll
    for (int i=0;i<2;i++){
      int it = tid + i*256;
      int gg = it & 3, key = it >> 2;
      int kk = kbase + key;
      int kr = kk/27, kc = kk - kr*27;
      int gr = wh*3 + kr - 12, gc = ww*3 + kc - 12;
      bool inb = (kk < 729) && ((unsigned)gr < 27u) && ((unsigned)gc < 27u);
      uint4 kd = make_uint4(0,0,0,0), vd = make_uint4(0,0,0,0);
      if (inb){
        const bf16* src = kvb + (size_t)(gr*27+gc)*512 + gg*8;
        kd = *(const uint4*)src;
        vd = *(const uint4*)(src + 256);
      }
      *(uint4*)&Kls[(gg*128 + key)*8] = kd;
      const unsigned short* vs = (const unsigned short*)&vd;
      #pragma unroll
      for (int e=0;e<8;e++) Vls[key*34 + gg*8 + e] = vs[e];
      if (gg == 0) maskls[key] = (inb && !(gr>=24 && gc>=24)) ? 0.f : -30000.f;
    }
    __syncthreads();

    // ---- S = Q K^T : 8 col-tiles of 16 keys ----
    f32x4 s[8];
    #pragma unroll
    for (int t=0;t<8;t++){
      bf16x8 kb = *(const bf16x8*)&Kls[(g*128 + t*16 + li)*8];
      f32x4 z = {0.f,0.f,0.f,0.f};
      s[t] = __builtin_amdgcn_mfma_f32_16x16x32_bf16(qa, kb, z, 0, 0, 0);
    }
    // mask (per key column)
    #pragma unroll
    for (int t=0;t<8;t++){
      float mk = maskls[t*16 + li];
      #pragma unroll
      for (int r=0;r<4;r++) s[t][r] += mk;
    }
    // ---- online softmax (rows = g*4+r, cols spread over li & tiles) ----
    float fac[4], ps[4];
    #pragma unroll
    for (int r=0;r<4;r++){
      float mt = s[0][r];
      #pragma unroll
      for (int t=1;t<8;t++) mt = fmaxf(mt, s[t][r]);
      mt = fmaxf(mt, __shfl_xor(mt, 1));
      mt = fmaxf(mt, __shfl_xor(mt, 2));
      mt = fmaxf(mt, __shfl_xor(mt, 4));
      mt = fmaxf(mt, __shfl_xor(mt, 8));
      float mn = fmaxf(mrow[r], mt);
      fac[r] = __expf(mrow[r] - mn);
      mrow[r] = mn;
      ps[r] = 0.f;
    }
    #pragma unroll
    for (int t=0;t<8;t++){
      #pragma unroll
      for (int r=0;r<4;r++){
        float p = __expf(s[t][r] - mrow[r]);
        s[t][r] = p;
        ps[r] += p;
      }
    }
    #pragma unroll
    for (int r=0;r<4;r++){
      ps[r] += __shfl_xor(ps[r], 1);
      ps[r] += __shfl_xor(ps[r], 2);
      ps[r] += __shfl_xor(ps[r], 4);
      ps[r] += __shfl_xor(ps[r], 8);
      lrow[r] = lrow[r]*fac[r] + ps[r];
      o0[r] *= fac[r];
      o1[r] *= fac[r];
    }
    // ---- P -> per-wave LDS (bf16, XOR-swizzled rows) ----
    #pragma unroll
    for (int t=0;t<8;t++){
      #pragma unroll
      for (int r=0;r<4;r++){
        int row = g*4 + r;
        int idx = (row*128 + t*16 + li) ^ ((row&7)<<3);
        Pls[wid][idx] = f2bfu(s[t][r]);
      }
    }
    // ---- O += P V  (4 key-chunks of 32) ----
    #pragma unroll
    for (int c=0;c<4;c++){
      int pidx = (li*128 + c*32 + g*8) ^ ((li&7)<<3);
      bf16x8 pa = *(const bf16x8*)&Pls[wid][pidx];
      bf16x8 vb0, vb1;
      #pragma unroll
      for (int e=0;e<8;e++){
        int key = c*32 + g*8 + e;
        vb0[e] = (short)Vls[key*34 + li];
        vb1[e] = (short)Vls[key*34 + 16 + li];
      }
      o0 = __builtin_amdgcn_mfma_f32_16x16x32_bf16(pa, vb0, o0, 0, 0, 0);
      o1 = __builtin_amdgcn_mfma_f32_16x16x32_bf16(pa, vb1, o1, 0, 0, 0);
    }
    __syncthreads();
  }

  // ---- epilogue: O /= l, write rows g*4+r ----
  #pragma unroll
  for (int r=0;r<4;r++){
    float rl = 1.f / lrow[r];
    int qr = wid*16 + g*4 + r;
    if (qr < 49){
      bf16* op = obuf + ((size_t)w*49 + qr)*256 + hh*32;
      op[li]      = f2bf(o0[r]*rl);
      op[16 + li] = f2bf(o1[r]*rl);
    }
  }
}

// ---------------- K4: out-proj + shortcut + ls1, window-reverse + crop -----
__global__ __launch_bounds__(256) void proj_kernel(
    const bf16* __restrict__ obuf, const float* __restrict__ x,
    const float* __restrict__ proj_w, const float* __restrict__ proj_b,
    const float* __restrict__ ls1, float* __restrict__ xobuf){
  __shared__ __align__(16) float ol[49*256];
  int tid = threadIdx.x;
  int w = blockIdx.x;
  int b = w/81, wi = w - b*81, wh = wi/9, ww = wi - wh*9;
  for (int idx=tid; idx<49*64; idx+=256){
    ushort4 raw = ((const ushort4*)(obuf + (size_t)w*49*256))[idx];
    union { unsigned int i; float f; } c0,c1,c2,c3;
    c0.i = ((unsigned int)raw.x)<<16; c1.i = ((unsigned int)raw.y)<<16;
    c2.i = ((unsigned int)raw.z)<<16; c3.i = ((unsigned int)raw.w)<<16;
    ((float4*)ol)[idx] = make_float4(c0.f,c1.f,c2.f,c3.f);
  }
  __syncthreads();
  float acc[49];
  #pragma unroll
  for (int t=0;t<49;t++) acc[t]=0.f;
  for (int k4=0;k4<64;k4++){
    float wv[4];
    #pragma unroll
    for (int j=0;j<4;j++) wv[j] = proj_w[(size_t)(k4*4+j)*256 + tid];
    #pragma unroll
    for (int t=0;t<49;t++){
      float xv[4];
      *(float4*)xv = ((const float4*)ol)[t*64+k4];
      acc[t] = fmaf(xv[0],wv[0],fmaf(xv[1],wv[1],fmaf(xv[2],wv[2],fmaf(xv[3],wv[3],acc[t]))));
    }
  }
  float pb = proj_b[tid];
  float l1 = ls1[tid];
  #pragma unroll
  for (int t=0;t<49;t++){
    int r=t/7, c=t-r*7;
    int gh=wh*7+r, gw=ww*7+c;
    if (gh<60 && gw<60){
      size_t p = (size_t)(b*3600 + gh*60 + gw)*256 + tid;
      float sc = x[p];
      xobuf[p] = sc + l1*(acc[t]+pb);
    }
  }
}

// ---------------- K5: LN + fc1 + GELU(erf) + fc2 + residual ----------------
__global__ __launch_bounds__(256) void mlp_kernel(
    const float* __restrict__ xobuf, const float* __restrict__ g,
    const float* __restrict__ bb, const float* __restrict__ fc1_w,
    const float* __restrict__ fc1_b, const float* __restrict__ fc2_w,
    const float* __restrict__ fc2_b, const float* __restrict__ ls2,
    float* __restrict__ out){
  __shared__ __align__(16) float xn[8*256];
  __shared__ __align__(16) float h1[8*1024];
  int tid = threadIdx.x, wid = tid>>6, lane = tid&63;
  int tok0 = blockIdx.x * 8;
  float4 g4 = ((const float4*)g)[lane];
  float4 b4 = ((const float4*)bb)[lane];
  #pragma unroll
  for (int tt=0; tt<2; tt++){
    int t = wid*2 + tt;
    float4 v = ((const float4*)(xobuf + (size_t)(tok0+t)*256))[lane];
    float s = v.x+v.y+v.z+v.w;
    float ss = v.x*v.x+v.y*v.y+v.z*v.z+v.w*v.w;
    #pragma unroll
    for (int off=32; off; off>>=1){ s += __shfl_xor(s,off); ss += __shfl_xor(ss,off); }
    float mean = s*(1.f/256.f);
    float var = fmaxf(ss*(1.f/256.f)-mean*mean, 0.f);
    float inv = rsqrtf(var+1e-5f);
    float4 o;
    o.x=(v.x-mean)*inv*g4.x+b4.x;
    o.y=(v.y-mean)*inv*g4.y+b4.y;
    o.z=(v.z-mean)*inv*g4.z+b4.z;
    o.w=(v.w-mean)*inv*g4.w+b4.w;
    ((float4*)xn)[t*64 + lane] = o;
  }
  __syncthreads();
  float acc[8][4];
  #pragma unroll
  for (int t=0;t<8;t++){
    #pragma unroll
    for (int c=0;c<4;c++) acc[t][c]=0.f;
  }
  for (int k4=0;k4<64;k4++){
    float xv[8][4];
    #pragma unroll
    for (int t=0;t<8;t++) *(float4*)&xv[t][0] = ((const float4*)xn)[t*64+k4];
    #pragma unroll
    for (int j=0;j<4;j++){
      int k = k4*4+j;
      const float* wr = fc1_w + (size_t)k*1024 + tid;
      float w0=wr[0], w1=wr[256], w2=wr[512], w3=wr[768];
      #pragma unroll
      for (int t=0;t<8;t++){
        float xvj = xv[t][j];
        acc[t][0]=fmaf(xvj,w0,acc[t][0]);
        acc[t][1]=fmaf(xvj,w1,acc[t][1]);
        acc[t][2]=fmaf(xvj,w2,acc[t][2]);
        acc[t][3]=fmaf(xvj,w3,acc[t][3]);
      }
    }
  }
  float fb[4];
  #pragma unroll
  for (int c=0;c<4;c++) fb[c] = fc1_b[tid + c*256];
  #pragma unroll
  for (int t=0;t<8;t++){
    #pragma unroll
    for (int c=0;c<4;c++){
      float h = acc[t][c] + fb[c];
      h = 0.5f*h*(1.f + erff(h*0.70710678118654752f));
      h1[t*1024 + tid + c*256] = h;
    }
  }
  __syncthreads();
  float a2[8];
  #pragma unroll
  for (int t=0;t<8;t++) a2[t]=0.f;
  for (int k4=0;k4<256;k4++){
    float hv[8][4];
    #pragma unroll
    for (int t=0;t<8;t++) *(float4*)&hv[t][0] = ((const float4*)h1)[t*256+k4];
    #pragma unroll
    for (int j=0;j<4;j++){
      int k = k4*4+j;
      float wv = fc2_w[(size_t)k*256 + tid];
      #pragma unroll
      for (int t=0;t<8;t++) a2[t] = fmaf(hv[t][j], wv, a2[t]);
    }
  }
  float c2 = fc2_b[tid];
  float l2 = ls2[tid];
  #pragma unroll
  for (int t=0;t<8;t++){
    size_t p = (size_t)(tok0+t)*256 + tid;
    out[p] = xobuf[p] + l2*(a2[t]+c2);
  }
}

extern "C" void kernel_launch(void* const* d_in, const int* in_sizes, int n_in,
                              void* d_out, int out_size, void* d_ws, size_t ws_size,
                              hipStream_t stream) {
  (void)in_sizes; (void)n_in; (void)out_size; (void)ws_size;
  const float* x      = (const float*)d_in[0];
  const float* y      = (const float*)d_in[1];
  const float* n1g    = (const float*)d_in[2];
  const float* n1b    = (const float*)d_in[3];
  const float* q_w    = (const float*)d_in[4];
  const float* kv_w   = (const float*)d_in[5];
  const float* proj_w = (const float*)d_in[6];
  const float* proj_b = (const float*)d_in[7];
  const float* n2g    = (const float*)d_in[8];
  const float* n2b    = (const float*)d_in[9];
  const float* fc1_w  = (const float*)d_in[10];
  const float* fc1_b  = (const float*)d_in[11];
  const float* fc2_w  = (const float*)d_in[12];
  const float* fc2_b  = (const float*)d_in[13];
  const float* ls1    = (const float*)d_in[14];
  const float* ls2    = (const float*)d_in[15];

  char* ws = (char*)d_ws;
  // Time-disjoint layout (22.9 MB):
  //   kvbuf bf16[4*729*512]   @ 0          live K1..K3
  //   qbuf  bf16[324*49*256]  @ 2,985,984  live K2..K3
  //   obuf  bf16[324*49*256]  @ 14,745,600 live K3..K4
  //   xobuf f32 [4*3600*256]  @ 0          live K4..K5 (overlays dead kv/q)
  bf16*  kvbuf = (bf16*)(ws);
  bf16*  qbuf  = (bf16*)(ws + 2985984);
  bf16*  obuf  = (bf16*)(ws + 14745600);
  float* xobuf = (float*)(ws);

  kv_kernel<<<729, 256, 0, stream>>>(y, n1g, n1b, kv_w, kvbuf);
  q_kernel<<<324, 256, 0, stream>>>(x, n1g, n1b, q_w, qbuf);
  attn_kernel<<<2592, 256, 0, stream>>>(qbuf, kvbuf, obuf);
  proj_kernel<<<324, 256, 0, stream>>>(obuf, x, proj_w, proj_b, ls1, xobuf);
  mlp_kernel<<<1800, 256, 0, stream>>>(xobuf, n2g, n2b, fc1_w, fc1_b, fc2_w, fc2_b, ls2,
                                       (float*)d_out);
}

// Round 4
// 470.163 us; speedup vs baseline: 8.4967x; 1.2972x over previous
//
#include <hip/hip_runtime.h>
#include <hip/hip_bf16.h>

typedef __hip_bfloat16 bf16;
typedef __attribute__((ext_vector_type(8))) short bf16x8;
typedef __attribute__((ext_vector_type(4))) float f32x4;

// Problem constants: B=4, H=W=60, C=256, HEADS=8, hd=32, WS=7 -> 9x9 windows/batch,
// 324 windows, 49 q/window, key window 27x27=729 gathered from 27x27 grid (stride 3,
// offset -12), corner mask (gr>=24 && gc>=24), NEG=-1000 (==0 weight in f32 softmax).
// All external I/O f32; staging buffers bf16.

__device__ __forceinline__ bf16 f2bf(float f){ return __float2bfloat16(f); }
__device__ __forceinline__ unsigned short f2bfu(float f){
  __hip_bfloat16 h = __float2bfloat16(f);
  return *(unsigned short*)&h;
}

// ---------------- K0: weight transpose + bf16 convert ----------------------
// W1T[n=1024][k=256] = fc1_w[k][n]; W2T[n=256][k=1024] = fc2_w[k][n].
__global__ __launch_bounds__(256) void wt_kernel(
    const float* __restrict__ fc1_w, const float* __restrict__ fc2_w,
    bf16* __restrict__ W1T, bf16* __restrict__ W2T){
  int gid = blockIdx.x*256 + threadIdx.x;
  if (gid < 262144){
    int n = gid >> 8, k = gid & 255;
    W1T[gid] = f2bf(fc1_w[(size_t)k*1024 + n]);
  } else {
    int o = gid - 262144;
    int n = o >> 10, k = o & 1023;
    W2T[o] = f2bf(fc2_w[(size_t)k*256 + n]);
  }
}

// ---------------- K1: LN(y) + kv projection (valid 27x27 grid only) --------
__global__ __launch_bounds__(256) void kv_kernel(
    const float* __restrict__ y, const float* __restrict__ g,
    const float* __restrict__ bb, const float* __restrict__ kv_w,
    bf16* __restrict__ kvbuf){
  __shared__ __align__(16) float xn[4*256];
  int tid = threadIdx.x, wid = tid >> 6, lane = tid & 63;
  int bs0 = blockIdx.x * 4;
  {
    int bs = bs0 + wid;
    float4 v = ((const float4*)(y + (size_t)bs*256))[lane];
    float s = v.x+v.y+v.z+v.w, ss = v.x*v.x+v.y*v.y+v.z*v.z+v.w*v.w;
    #pragma unroll
    for (int off=32; off; off>>=1){ s += __shfl_xor(s,off); ss += __shfl_xor(ss,off); }
    float mean = s*(1.f/256.f);
    float var  = fmaxf(ss*(1.f/256.f) - mean*mean, 0.f);
    float inv  = rsqrtf(var + 1e-5f);
    float4 g4 = ((const float4*)g)[lane];
    float4 b4 = ((const float4*)bb)[lane];
    float4 o;
    o.x=(v.x-mean)*inv*g4.x+b4.x;
    o.y=(v.y-mean)*inv*g4.y+b4.y;
    o.z=(v.z-mean)*inv*g4.z+b4.z;
    o.w=(v.w-mean)*inv*g4.w+b4.w;
    ((float4*)xn)[wid*64 + lane] = o;
  }
  __syncthreads();
  float acc[4][2];
  #pragma unroll
  for (int t=0;t<4;t++){ acc[t][0]=0.f; acc[t][1]=0.f; }
  for (int k4=0;k4<64;k4++){
    float xv[4][4];
    #pragma unroll
    for (int t=0;t<4;t++) *(float4*)&xv[t][0] = ((const float4*)xn)[t*64+k4];
    #pragma unroll
    for (int j=0;j<4;j++){
      int k = k4*4+j;
      float w0 = kv_w[(size_t)k*512 + tid];
      float w1 = kv_w[(size_t)k*512 + 256 + tid];
      #pragma unroll
      for (int t=0;t<4;t++){
        acc[t][0] = fmaf(xv[t][j], w0, acc[t][0]);
        acc[t][1] = fmaf(xv[t][j], w1, acc[t][1]);
      }
    }
  }
  #pragma unroll
  for (int t=0;t<4;t++){
    kvbuf[(size_t)(bs0+t)*512 + tid]       = f2bf(acc[t][0]);
    kvbuf[(size_t)(bs0+t)*512 + 256 + tid] = f2bf(acc[t][1]);
  }
}

// ---------------- K2: per-window LN(xw) + q projection (scale folded) ------
__global__ __launch_bounds__(256) void q_kernel(
    const float* __restrict__ x, const float* __restrict__ g,
    const float* __restrict__ bb, const float* __restrict__ q_w,
    bf16* __restrict__ qbuf){
  __shared__ __align__(16) float xn[49*256];
  int tid = threadIdx.x, wid = tid>>6, lane = tid&63;
  int w = blockIdx.x;
  int b = w/81, wi = w - b*81, wh = wi/9, ww = wi - wh*9;
  float4 g4 = ((const float4*)g)[lane];
  float4 b4 = ((const float4*)bb)[lane];
  for (int t=wid; t<49; t+=4){
    int r = t/7, c = t - r*7;
    int gh = wh*7 + r, gw = ww*7 + c;
    float4 v = make_float4(0.f,0.f,0.f,0.f);
    if (gh < 60 && gw < 60){
      v = ((const float4*)(x + (size_t)(b*3600 + gh*60 + gw)*256))[lane];
    }
    float s=v.x+v.y+v.z+v.w, ss=v.x*v.x+v.y*v.y+v.z*v.z+v.w*v.w;
    #pragma unroll
    for (int off=32; off; off>>=1){ s += __shfl_xor(s,off); ss += __shfl_xor(ss,off); }
    float mean = s*(1.f/256.f);
    float var = fmaxf(ss*(1.f/256.f)-mean*mean, 0.f);
    float inv = rsqrtf(var+1e-5f);
    float4 o;
    o.x=(v.x-mean)*inv*g4.x+b4.x;
    o.y=(v.y-mean)*inv*g4.y+b4.y;
    o.z=(v.z-mean)*inv*g4.z+b4.z;
    o.w=(v.w-mean)*inv*g4.w+b4.w;
    ((float4*)xn)[t*64 + lane] = o;
  }
  __syncthreads();
  float acc[49];
  #pragma unroll
  for (int t=0;t<49;t++) acc[t]=0.f;
  for (int k4=0;k4<64;k4++){
    float wv[4];
    #pragma unroll
    for (int j=0;j<4;j++) wv[j] = q_w[(size_t)(k4*4+j)*256 + tid];
    #pragma unroll
    for (int t=0;t<49;t++){
      float xv[4];
      *(float4*)xv = ((const float4*)xn)[t*64+k4];
      acc[t] = fmaf(xv[0],wv[0],fmaf(xv[1],wv[1],fmaf(xv[2],wv[2],fmaf(xv[3],wv[3],acc[t]))));
    }
  }
  bf16* qb = qbuf + (size_t)w*49*256 + tid;
  #pragma unroll
  for (int t=0;t<49;t++) qb[t*256] = f2bf(acc[t]*0.17677669529663689f); // hd^-0.5 folded
}

// ---------------- K3: flash-style MFMA attention ---------------------------
__global__ __launch_bounds__(256) void attn_kernel(
    const bf16* __restrict__ qbuf, const bf16* __restrict__ kvbuf,
    bf16* __restrict__ obuf){
  __shared__ __align__(16) unsigned short Kls[4*128*8];   // [g][key][e] 8 KB
  __shared__ __align__(16) unsigned short Vls[128*34];    // [key][d] pad-34, 8.5 KB
  __shared__ __align__(16) float maskls[128];
  __shared__ __align__(16) unsigned short Pls[4][16*128]; // per-wave P, swizzled, 16 KB

  int tid = threadIdx.x, wid = tid>>6, lane = tid&63;
  int g = lane>>4, li = lane&15;
  int blk = blockIdx.x;
  int w = blk >> 3, hh = blk & 7;
  int b = w/81, wi = w - b*81, wh = wi/9, ww = wi - wh*9;
  const bf16* kvb = kvbuf + (size_t)b*729*512 + hh*32;

  bf16x8 qa;
  #pragma unroll
  for (int e=0;e<8;e++) qa[e]=0;
  int qrow = wid*16 + li;
  if (qrow < 49){
    qa = *(const bf16x8*)(qbuf + ((size_t)w*49+qrow)*256 + hh*32 + g*8);
  }

  f32x4 o0 = {0.f,0.f,0.f,0.f}, o1 = {0.f,0.f,0.f,0.f};
  float mrow[4], lrow[4];
  #pragma unroll
  for (int r=0;r<4;r++){ mrow[r] = -3.0e38f; lrow[r] = 0.f; }

  for (int tile=0; tile<6; tile++){
    int kbase = tile*128;
    #pragma unroll
    for (int i=0;i<2;i++){
      int it = tid + i*256;
      int gg = it & 3, key = it >> 2;
      int kk = kbase + key;
      int kr = kk/27, kc = kk - kr*27;
      int gr = wh*3 + kr - 12, gc = ww*3 + kc - 12;
      bool inb = (kk < 729) && ((unsigned)gr < 27u) && ((unsigned)gc < 27u);
      uint4 kd = make_uint4(0,0,0,0), vd = make_uint4(0,0,0,0);
      if (inb){
        const bf16* src = kvb + (size_t)(gr*27+gc)*512 + gg*8;
        kd = *(const uint4*)src;
        vd = *(const uint4*)(src + 256);
      }
      *(uint4*)&Kls[(gg*128 + key)*8] = kd;
      const unsigned short* vs = (const unsigned short*)&vd;
      #pragma unroll
      for (int e=0;e<8;e++) Vls[key*34 + gg*8 + e] = vs[e];
      if (gg == 0) maskls[key] = (inb && !(gr>=24 && gc>=24)) ? 0.f : -30000.f;
    }
    __syncthreads();

    f32x4 s[8];
    #pragma unroll
    for (int t=0;t<8;t++){
      bf16x8 kb = *(const bf16x8*)&Kls[(g*128 + t*16 + li)*8];
      f32x4 z = {0.f,0.f,0.f,0.f};
      s[t] = __builtin_amdgcn_mfma_f32_16x16x32_bf16(qa, kb, z, 0, 0, 0);
    }
    #pragma unroll
    for (int t=0;t<8;t++){
      float mk = maskls[t*16 + li];
      #pragma unroll
      for (int r=0;r<4;r++) s[t][r] += mk;
    }
    float fac[4], ps[4];
    #pragma unroll
    for (int r=0;r<4;r++){
      float mt = s[0][r];
      #pragma unroll
      for (int t=1;t<8;t++) mt = fmaxf(mt, s[t][r]);
      mt = fmaxf(mt, __shfl_xor(mt, 1));
      mt = fmaxf(mt, __shfl_xor(mt, 2));
      mt = fmaxf(mt, __shfl_xor(mt, 4));
      mt = fmaxf(mt, __shfl_xor(mt, 8));
      float mn = fmaxf(mrow[r], mt);
      fac[r] = __expf(mrow[r] - mn);
      mrow[r] = mn;
      ps[r] = 0.f;
    }
    #pragma unroll
    for (int t=0;t<8;t++){
      #pragma unroll
      for (int r=0;r<4;r++){
        float p = __expf(s[t][r] - mrow[r]);
        s[t][r] = p;
        ps[r] += p;
      }
    }
    #pragma unroll
    for (int r=0;r<4;r++){
      ps[r] += __shfl_xor(ps[r], 1);
      ps[r] += __shfl_xor(ps[r], 2);
      ps[r] += __shfl_xor(ps[r], 4);
      ps[r] += __shfl_xor(ps[r], 8);
      lrow[r] = lrow[r]*fac[r] + ps[r];
      o0[r] *= fac[r];
      o1[r] *= fac[r];
    }
    #pragma unroll
    for (int t=0;t<8;t++){
      #pragma unroll
      for (int r=0;r<4;r++){
        int row = g*4 + r;
        int idx = (row*128 + t*16 + li) ^ ((row&7)<<3);
        Pls[wid][idx] = f2bfu(s[t][r]);
      }
    }
    #pragma unroll
    for (int c=0;c<4;c++){
      int pidx = (li*128 + c*32 + g*8) ^ ((li&7)<<3);
      bf16x8 pa = *(const bf16x8*)&Pls[wid][pidx];
      bf16x8 vb0, vb1;
      #pragma unroll
      for (int e=0;e<8;e++){
        int key = c*32 + g*8 + e;
        vb0[e] = (short)Vls[key*34 + li];
        vb1[e] = (short)Vls[key*34 + 16 + li];
      }
      o0 = __builtin_amdgcn_mfma_f32_16x16x32_bf16(pa, vb0, o0, 0, 0, 0);
      o1 = __builtin_amdgcn_mfma_f32_16x16x32_bf16(pa, vb1, o1, 0, 0, 0);
    }
    __syncthreads();
  }

  #pragma unroll
  for (int r=0;r<4;r++){
    float rl = 1.f / lrow[r];
    int qr = wid*16 + g*4 + r;
    if (qr < 49){
      bf16* op = obuf + ((size_t)w*49 + qr)*256 + hh*32;
      op[li]      = f2bf(o0[r]*rl);
      op[16 + li] = f2bf(o1[r]*rl);
    }
  }
}

// ---------------- K4: out-proj + shortcut + ls1, window-reverse + crop -----
__global__ __launch_bounds__(256) void proj_kernel(
    const bf16* __restrict__ obuf, const float* __restrict__ x,
    const float* __restrict__ proj_w, const float* __restrict__ proj_b,
    const float* __restrict__ ls1, float* __restrict__ xobuf){
  __shared__ __align__(16) float ol[49*256];
  int tid = threadIdx.x;
  int w = blockIdx.x;
  int b = w/81, wi = w - b*81, wh = wi/9, ww = wi - wh*9;
  for (int idx=tid; idx<49*64; idx+=256){
    ushort4 raw = ((const ushort4*)(obuf + (size_t)w*49*256))[idx];
    union { unsigned int i; float f; } c0,c1,c2,c3;
    c0.i = ((unsigned int)raw.x)<<16; c1.i = ((unsigned int)raw.y)<<16;
    c2.i = ((unsigned int)raw.z)<<16; c3.i = ((unsigned int)raw.w)<<16;
    ((float4*)ol)[idx] = make_float4(c0.f,c1.f,c2.f,c3.f);
  }
  __syncthreads();
  float acc[49];
  #pragma unroll
  for (int t=0;t<49;t++) acc[t]=0.f;
  for (int k4=0;k4<64;k4++){
    float wv[4];
    #pragma unroll
    for (int j=0;j<4;j++) wv[j] = proj_w[(size_t)(k4*4+j)*256 + tid];
    #pragma unroll
    for (int t=0;t<49;t++){
      float xv[4];
      *(float4*)xv = ((const float4*)ol)[t*64+k4];
      acc[t] = fmaf(xv[0],wv[0],fmaf(xv[1],wv[1],fmaf(xv[2],wv[2],fmaf(xv[3],wv[3],acc[t]))));
    }
  }
  float pb = proj_b[tid];
  float l1 = ls1[tid];
  #pragma unroll
  for (int t=0;t<49;t++){
    int r=t/7, c=t-r*7;
    int gh=wh*7+r, gw=ww*7+c;
    if (gh<60 && gw<60){
      size_t p = (size_t)(b*3600 + gh*60 + gw)*256 + tid;
      float sc = x[p];
      xobuf[p] = sc + l1*(acc[t]+pb);
    }
  }
}

// ---------------- K5: MFMA MLP: LN + fc1 + GELU + fc2 + residual -----------
// 900 blocks x 16 tokens, 256 threads (4 waves). Wave w owns out-cols
// [w*64, w*64+64) and H-col slice [j*256 + w*64, +64) per j-iteration.
// B-frags loaded straight from L2-resident transposed bf16 weights.
__global__ __launch_bounds__(256) void mlp_kernel(
    const float* __restrict__ xobuf, const float* __restrict__ g,
    const float* __restrict__ bb, const bf16* __restrict__ W1T,
    const float* __restrict__ fc1_b, const bf16* __restrict__ W2T,
    const float* __restrict__ fc2_b, const float* __restrict__ ls2,
    float* __restrict__ out){
  __shared__ __align__(16) unsigned short xn[16*256];  // swizzled bf16, 8 KB
  __shared__ __align__(16) unsigned short Hls[16*256]; // swizzled bf16, 8 KB
  int tid = threadIdx.x, wid = tid>>6, lane = tid&63;
  int li = lane&15, lg = lane>>4;
  int tok0 = blockIdx.x * 16;
  // ---- LN of 16 tokens -> xn (bf16, XOR-swizzled rows) ----
  {
    float4 g4 = ((const float4*)g)[lane];
    float4 b4 = ((const float4*)bb)[lane];
    #pragma unroll
    for (int tt=0; tt<4; tt++){
      int t = wid*4 + tt;
      float4 v = ((const float4*)(xobuf + (size_t)(tok0+t)*256))[lane];
      float s = v.x+v.y+v.z+v.w;
      float ss = v.x*v.x+v.y*v.y+v.z*v.z+v.w*v.w;
      #pragma unroll
      for (int off=32; off; off>>=1){ s += __shfl_xor(s,off); ss += __shfl_xor(ss,off); }
      float mean = s*(1.f/256.f);
      float var = fmaxf(ss*(1.f/256.f)-mean*mean, 0.f);
      float inv = rsqrtf(var+1e-5f);
      ushort4 pk;
      pk.x = f2bfu((v.x-mean)*inv*g4.x+b4.x);
      pk.y = f2bfu((v.y-mean)*inv*g4.y+b4.y);
      pk.z = f2bfu((v.z-mean)*inv*g4.z+b4.z);
      pk.w = f2bfu((v.w-mean)*inv*g4.w+b4.w);
      int idx = (t*256 + lane*4) ^ ((t&7)<<3);
      *(ushort4*)&xn[idx] = pk;
    }
  }
  __syncthreads();
  // ---- A-frags for fc1 (shared by all 4 waves; rows = 16 tokens) ----
  bf16x8 a1[8];
  #pragma unroll
  for (int ks=0; ks<8; ks++){
    int idx = (li*256 + ks*32 + lg*8) ^ ((li&7)<<3);
    a1[ks] = *(const bf16x8*)&xn[idx];
  }
  f32x4 oacc[4];
  #pragma unroll
  for (int nt=0; nt<4; nt++) oacc[nt] = (f32x4){0.f,0.f,0.f,0.f};

  for (int j=0; j<4; j++){
    // fc1 + GELU -> Hls (wave's 64-col slice of the 256-col j-tile)
    #pragma unroll
    for (int nn=0; nn<4; nn++){
      int ncol = j*256 + wid*64 + nn*16 + li;      // global H col
      const bf16* wp = W1T + (size_t)ncol*256 + lg*8;
      f32x4 hc = {0.f,0.f,0.f,0.f};
      #pragma unroll
      for (int ks=0; ks<8; ks++){
        bf16x8 bfrag = *(const bf16x8*)(wp + ks*32);
        hc = __builtin_amdgcn_mfma_f32_16x16x32_bf16(a1[ks], bfrag, hc, 0, 0, 0);
      }
      float bias = fc1_b[ncol];
      int colLoc = wid*64 + nn*16 + li;
      #pragma unroll
      for (int r=0; r<4; r++){
        float h = hc[r] + bias;
        float z = 0.7978845608f*(h + 0.044715f*h*h*h);   // tanh-approx GELU
        z = fminf(fmaxf(z, -15.f), 15.f);
        float e = __expf(2.f*z);
        float gv = 0.5f*h*(1.f + (e-1.f)/(e+1.f));
        int row = lg*4 + r;
        int idx = (row*256 + colLoc) ^ ((row&7)<<3);
        Hls[idx] = f2bfu(gv);
      }
    }
    __syncthreads();
    // fc2: oacc[nt] += H(16x256) x W2[jslice, wave cols]
    bf16x8 a2[8];
    #pragma unroll
    for (int ks=0; ks<8; ks++){
      int idx = (li*256 + ks*32 + lg*8) ^ ((li&7)<<3);
      a2[ks] = *(const bf16x8*)&Hls[idx];
    }
    #pragma unroll
    for (int nt=0; nt<4; nt++){
      int ncol2 = wid*64 + nt*16 + li;              // global out col
      const bf16* wp2 = W2T + (size_t)ncol2*1024 + j*256 + lg*8;
      #pragma unroll
      for (int ks=0; ks<8; ks++){
        bf16x8 bfrag = *(const bf16x8*)(wp2 + ks*32);
        oacc[nt] = __builtin_amdgcn_mfma_f32_16x16x32_bf16(a2[ks], bfrag, oacc[nt], 0, 0, 0);
      }
    }
    __syncthreads();
  }
  // ---- epilogue: residual + ls2 ----
  #pragma unroll
  for (int nt=0; nt<4; nt++){
    int col = wid*64 + nt*16 + li;
    float l2 = ls2[col];
    float cb = fc2_b[col];
    #pragma unroll
    for (int r=0; r<4; r++){
      int tok = tok0 + lg*4 + r;
      size_t p = (size_t)tok*256 + col;
      out[p] = xobuf[p] + l2*(oacc[nt][r] + cb);
    }
  }
}

extern "C" void kernel_launch(void* const* d_in, const int* in_sizes, int n_in,
                              void* d_out, int out_size, void* d_ws, size_t ws_size,
                              hipStream_t stream) {
  (void)in_sizes; (void)n_in; (void)out_size; (void)ws_size;
  const float* x      = (const float*)d_in[0];
  const float* y      = (const float*)d_in[1];
  const float* n1g    = (const float*)d_in[2];
  const float* n1b    = (const float*)d_in[3];
  const float* q_w    = (const float*)d_in[4];
  const float* kv_w   = (const float*)d_in[5];
  const float* proj_w = (const float*)d_in[6];
  const float* proj_b = (const float*)d_in[7];
  const float* n2g    = (const float*)d_in[8];
  const float* n2b    = (const float*)d_in[9];
  const float* fc1_w  = (const float*)d_in[10];
  const float* fc1_b  = (const float*)d_in[11];
  const float* fc2_w  = (const float*)d_in[12];
  const float* fc2_b  = (const float*)d_in[13];
  const float* ls1    = (const float*)d_in[14];
  const float* ls2    = (const float*)d_in[15];

  char* ws = (char*)d_ws;
  // Workspace (23.9 MB):
  //   kvbuf bf16[4*729*512]   @ 0          live K1..K3
  //   qbuf  bf16[324*49*256]  @ 2,985,984  live K2..K3
  //   obuf  bf16[324*49*256]  @ 14,745,600 live K3..K4
  //   xobuf f32 [4*3600*256]  @ 0          live K4..K5 (overlays dead kv/q)
  //   W1T   bf16[1024*256]    @ 22,874,112 live K0..K5
  //   W2T   bf16[256*1024]    @ 23,398,400 live K0..K5
  bf16*  kvbuf = (bf16*)(ws);
  bf16*  qbuf  = (bf16*)(ws + 2985984);
  bf16*  obuf  = (bf16*)(ws + 14745600);
  float* xobuf = (float*)(ws);
  bf16*  W1T   = (bf16*)(ws + 22874112);
  bf16*  W2T   = (bf16*)(ws + 23398400);

  wt_kernel<<<2048, 256, 0, stream>>>(fc1_w, fc2_w, W1T, W2T);
  kv_kernel<<<729, 256, 0, stream>>>(y, n1g, n1b, kv_w, kvbuf);
  q_kernel<<<324, 256, 0, stream>>>(x, n1g, n1b, q_w, qbuf);
  attn_kernel<<<2592, 256, 0, stream>>>(qbuf, kvbuf, obuf);
  proj_kernel<<<324, 256, 0, stream>>>(obuf, x, proj_w, proj_b, ls1, xobuf);
  mlp_kernel<<<900, 256, 0, stream>>>(xobuf, n2g, n2b, W1T, fc1_b, W2T, fc2_b, ls2,
                                      (float*)d_out);
}

// Round 5
// 332.420 us; speedup vs baseline: 12.0175x; 1.4144x over previous
//
#include <hip/hip_runtime.h>
#include <hip/hip_bf16.h>

typedef __hip_bfloat16 bf16;
typedef __attribute__((ext_vector_type(8))) short bf16x8;
typedef __attribute__((ext_vector_type(4))) float f32x4;

// Problem constants: B=4, H=W=60, C=256, HEADS=8, hd=32, WS=7 -> 9x9 windows/batch,
// 324 windows, 49 q/window, key window 27x27=729 gathered from 27x27 grid (stride 3,
// offset -12), corner mask (gr>=24 && gc>=24), NEG=-1000 (==0 weight in f32 softmax).
// All external I/O f32; staging buffers bf16.
//
// Verified MFMA lane mapping (16x16x32 bf16, from passing rounds 3-4):
//   A-frag: lane(li=lane&15, lg=lane>>4) holds A[row=li][k=kc*32+lg*8+e]
//   B-frag: lane holds B[col=li][k=kc*32+lg*8+e]
//   C/D   : [row=lg*4+r][col=li]
// Weights pre-packed in fragment order: F[((nt*NKC+kc)*64+lane)*8+e] = W[k][nt*16+li]
// so a wave's B-frag load is 64 lanes x 16B contiguous (coalesced 1KB from L2).

__device__ __forceinline__ bf16 f2bf(float f){ return __float2bfloat16(f); }
__device__ __forceinline__ unsigned short f2bfu(float f){
  __hip_bfloat16 h = __float2bfloat16(f);
  return *(unsigned short*)&h;
}

// ---------------- K0: pack fc1/fc2/proj weights into fragment order --------
__global__ __launch_bounds__(256) void wt_kernel(
    const float* __restrict__ fc1_w, const float* __restrict__ fc2_w,
    const float* __restrict__ proj_w,
    bf16* __restrict__ W1F, bf16* __restrict__ W2F, bf16* __restrict__ PWF){
  int gid = blockIdx.x*256 + threadIdx.x;
  if (gid < 262144){               // W1F: K=256 (kc<8), N=1024 (nt<64)
    int e=gid&7, lane=(gid>>3)&63, kc=(gid>>9)&7, nt=gid>>12;
    int li=lane&15, lg=lane>>4;
    W1F[gid] = f2bf(fc1_w[(size_t)(kc*32+lg*8+e)*1024 + nt*16+li]);
  } else if (gid < 524288){        // W2F: K=1024 (kc<32), N=256 (nt<16)
    int o = gid - 262144;
    int e=o&7, lane=(o>>3)&63, kc=(o>>9)&31, nt=o>>14;
    int li=lane&15, lg=lane>>4;
    W2F[o] = f2bf(fc2_w[(size_t)(kc*32+lg*8+e)*256 + nt*16+li]);
  } else {                         // PWF: K=256 (kc<8), N=256 (nt<16)
    int o = gid - 524288;
    int e=o&7, lane=(o>>3)&63, kc=(o>>9)&7, nt=o>>12;
    int li=lane&15, lg=lane>>4;
    PWF[o] = f2bf(proj_w[(size_t)(kc*32+lg*8+e)*256 + nt*16+li]);
  }
}

// ---------------- K1: LN(y) + kv projection (valid 27x27 grid only) --------
__global__ __launch_bounds__(256) void kv_kernel(
    const float* __restrict__ y, const float* __restrict__ g,
    const float* __restrict__ bb, const float* __restrict__ kv_w,
    bf16* __restrict__ kvbuf){
  __shared__ __align__(16) float xn[4*256];
  int tid = threadIdx.x, wid = tid >> 6, lane = tid & 63;
  int bs0 = blockIdx.x * 4;
  {
    int bs = bs0 + wid;
    float4 v = ((const float4*)(y + (size_t)bs*256))[lane];
    float s = v.x+v.y+v.z+v.w, ss = v.x*v.x+v.y*v.y+v.z*v.z+v.w*v.w;
    #pragma unroll
    for (int off=32; off; off>>=1){ s += __shfl_xor(s,off); ss += __shfl_xor(ss,off); }
    float mean = s*(1.f/256.f);
    float var  = fmaxf(ss*(1.f/256.f) - mean*mean, 0.f);
    float inv  = rsqrtf(var + 1e-5f);
    float4 g4 = ((const float4*)g)[lane];
    float4 b4 = ((const float4*)bb)[lane];
    float4 o;
    o.x=(v.x-mean)*inv*g4.x+b4.x;
    o.y=(v.y-mean)*inv*g4.y+b4.y;
    o.z=(v.z-mean)*inv*g4.z+b4.z;
    o.w=(v.w-mean)*inv*g4.w+b4.w;
    ((float4*)xn)[wid*64 + lane] = o;
  }
  __syncthreads();
  float acc[4][2];
  #pragma unroll
  for (int t=0;t<4;t++){ acc[t][0]=0.f; acc[t][1]=0.f; }
  for (int k4=0;k4<64;k4++){
    float xv[4][4];
    #pragma unroll
    for (int t=0;t<4;t++) *(float4*)&xv[t][0] = ((const float4*)xn)[t*64+k4];
    #pragma unroll
    for (int j=0;j<4;j++){
      int k = k4*4+j;
      float w0 = kv_w[(size_t)k*512 + tid];
      float w1 = kv_w[(size_t)k*512 + 256 + tid];
      #pragma unroll
      for (int t=0;t<4;t++){
        acc[t][0] = fmaf(xv[t][j], w0, acc[t][0]);
        acc[t][1] = fmaf(xv[t][j], w1, acc[t][1]);
      }
    }
  }
  #pragma unroll
  for (int t=0;t<4;t++){
    kvbuf[(size_t)(bs0+t)*512 + tid]       = f2bf(acc[t][0]);
    kvbuf[(size_t)(bs0+t)*512 + 256 + tid] = f2bf(acc[t][1]);
  }
}

// ---------------- K2: per-window LN(xw) + q projection (scale folded) ------
__global__ __launch_bounds__(256) void q_kernel(
    const float* __restrict__ x, const float* __restrict__ g,
    const float* __restrict__ bb, const float* __restrict__ q_w,
    bf16* __restrict__ qbuf){
  __shared__ __align__(16) float xn[49*256];
  int tid = threadIdx.x, wid = tid>>6, lane = tid&63;
  int w = blockIdx.x;
  int b = w/81, wi = w - b*81, wh = wi/9, ww = wi - wh*9;
  float4 g4 = ((const float4*)g)[lane];
  float4 b4 = ((const float4*)bb)[lane];
  for (int t=wid; t<49; t+=4){
    int r = t/7, c = t - r*7;
    int gh = wh*7 + r, gw = ww*7 + c;
    float4 v = make_float4(0.f,0.f,0.f,0.f);
    if (gh < 60 && gw < 60){
      v = ((const float4*)(x + (size_t)(b*3600 + gh*60 + gw)*256))[lane];
    }
    float s=v.x+v.y+v.z+v.w, ss=v.x*v.x+v.y*v.y+v.z*v.z+v.w*v.w;
    #pragma unroll
    for (int off=32; off; off>>=1){ s += __shfl_xor(s,off); ss += __shfl_xor(ss,off); }
    float mean = s*(1.f/256.f);
    float var = fmaxf(ss*(1.f/256.f)-mean*mean, 0.f);
    float inv = rsqrtf(var+1e-5f);
    float4 o;
    o.x=(v.x-mean)*inv*g4.x+b4.x;
    o.y=(v.y-mean)*inv*g4.y+b4.y;
    o.z=(v.z-mean)*inv*g4.z+b4.z;
    o.w=(v.w-mean)*inv*g4.w+b4.w;
    ((float4*)xn)[t*64 + lane] = o;
  }
  __syncthreads();
  float acc[49];
  #pragma unroll
  for (int t=0;t<49;t++) acc[t]=0.f;
  for (int k4=0;k4<64;k4++){
    float wv[4];
    #pragma unroll
    for (int j=0;j<4;j++) wv[j] = q_w[(size_t)(k4*4+j)*256 + tid];
    #pragma unroll
    for (int t=0;t<49;t++){
      float xv[4];
      *(float4*)xv = ((const float4*)xn)[t*64+k4];
      acc[t] = fmaf(xv[0],wv[0],fmaf(xv[1],wv[1],fmaf(xv[2],wv[2],fmaf(xv[3],wv[3],acc[t]))));
    }
  }
  bf16* qb = qbuf + (size_t)w*49*256 + tid;
  #pragma unroll
  for (int t=0;t<49;t++) qb[t*256] = f2bf(acc[t]*0.17677669529663689f); // hd^-0.5 folded
}

// ---------------- K3: flash-style MFMA attention ---------------------------
__global__ __launch_bounds__(256) void attn_kernel(
    const bf16* __restrict__ qbuf, const bf16* __restrict__ kvbuf,
    bf16* __restrict__ obuf){
  __shared__ __align__(16) unsigned short Kls[4*128*8];   // [g][key][e] 8 KB
  __shared__ __align__(16) unsigned short Vls[128*34];    // [key][d] pad-34, 8.5 KB
  __shared__ __align__(16) float maskls[128];
  __shared__ __align__(16) unsigned short Pls[4][16*128]; // per-wave P, swizzled, 16 KB

  int tid = threadIdx.x, wid = tid>>6, lane = tid&63;
  int g = lane>>4, li = lane&15;
  int blk = blockIdx.x;
  int w = blk >> 3, hh = blk & 7;
  int b = w/81, wi = w - b*81, wh = wi/9, ww = wi - wh*9;
  const bf16* kvb = kvbuf + (size_t)b*729*512 + hh*32;

  bf16x8 qa;
  #pragma unroll
  for (int e=0;e<8;e++) qa[e]=0;
  int qrow = wid*16 + li;
  if (qrow < 49){
    qa = *(const bf16x8*)(qbuf + ((size_t)w*49+qrow)*256 + hh*32 + g*8);
  }

  f32x4 o0 = {0.f,0.f,0.f,0.f}, o1 = {0.f,0.f,0.f,0.f};
  float mrow[4], lrow[4];
  #pragma unroll
  for (int r=0;r<4;r++){ mrow[r] = -3.0e38f; lrow[r] = 0.f; }

  for (int tile=0; tile<6; tile++){
    int kbase = tile*128;
    #pragma unroll
    for (int i=0;i<2;i++){
      int it = tid + i*256;
      int gg = it & 3, key = it >> 2;
      int kk = kbase + key;
      int kr = kk/27, kc = kk - kr*27;
      int gr = wh*3 + kr - 12, gc = ww*3 + kc - 12;
      bool inb = (kk < 729) && ((unsigned)gr < 27u) && ((unsigned)gc < 27u);
      uint4 kd = make_uint4(0,0,0,0), vd = make_uint4(0,0,0,0);
      if (inb){
        const bf16* src = kvb + (size_t)(gr*27+gc)*512 + gg*8;
        kd = *(const uint4*)src;
        vd = *(const uint4*)(src + 256);
      }
      *(uint4*)&Kls[(gg*128 + key)*8] = kd;
      const unsigned short* vs = (const unsigned short*)&vd;
      #pragma unroll
      for (int e=0;e<8;e++) Vls[key*34 + gg*8 + e] = vs[e];
      if (gg == 0) maskls[key] = (inb && !(gr>=24 && gc>=24)) ? 0.f : -30000.f;
    }
    __syncthreads();

    f32x4 s[8];
    #pragma unroll
    for (int t=0;t<8;t++){
      bf16x8 kb = *(const bf16x8*)&Kls[(g*128 + t*16 + li)*8];
      f32x4 z = {0.f,0.f,0.f,0.f};
      s[t] = __builtin_amdgcn_mfma_f32_16x16x32_bf16(qa, kb, z, 0, 0, 0);
    }
    #pragma unroll
    for (int t=0;t<8;t++){
      float mk = maskls[t*16 + li];
      #pragma unroll
      for (int r=0;r<4;r++) s[t][r] += mk;
    }
    float fac[4], ps[4];
    #pragma unroll
    for (int r=0;r<4;r++){
      float mt = s[0][r];
      #pragma unroll
      for (int t=1;t<8;t++) mt = fmaxf(mt, s[t][r]);
      mt = fmaxf(mt, __shfl_xor(mt, 1));
      mt = fmaxf(mt, __shfl_xor(mt, 2));
      mt = fmaxf(mt, __shfl_xor(mt, 4));
      mt = fmaxf(mt, __shfl_xor(mt, 8));
      float mn = fmaxf(mrow[r], mt);
      fac[r] = __expf(mrow[r] - mn);
      mrow[r] = mn;
      ps[r] = 0.f;
    }
    #pragma unroll
    for (int t=0;t<8;t++){
      #pragma unroll
      for (int r=0;r<4;r++){
        float p = __expf(s[t][r] - mrow[r]);
        s[t][r] = p;
        ps[r] += p;
      }
    }
    #pragma unroll
    for (int r=0;r<4;r++){
      ps[r] += __shfl_xor(ps[r], 1);
      ps[r] += __shfl_xor(ps[r], 2);
      ps[r] += __shfl_xor(ps[r], 4);
      ps[r] += __shfl_xor(ps[r], 8);
      lrow[r] = lrow[r]*fac[r] + ps[r];
      o0[r] *= fac[r];
      o1[r] *= fac[r];
    }
    #pragma unroll
    for (int t=0;t<8;t++){
      #pragma unroll
      for (int r=0;r<4;r++){
        int row = g*4 + r;
        int idx = (row*128 + t*16 + li) ^ ((row&7)<<3);
        Pls[wid][idx] = f2bfu(s[t][r]);
      }
    }
    #pragma unroll
    for (int c=0;c<4;c++){
      int pidx = (li*128 + c*32 + g*8) ^ ((li&7)<<3);
      bf16x8 pa = *(const bf16x8*)&Pls[wid][pidx];
      bf16x8 vb0, vb1;
      #pragma unroll
      for (int e=0;e<8;e++){
        int key = c*32 + g*8 + e;
        vb0[e] = (short)Vls[key*34 + li];
        vb1[e] = (short)Vls[key*34 + 16 + li];
      }
      o0 = __builtin_amdgcn_mfma_f32_16x16x32_bf16(pa, vb0, o0, 0, 0, 0);
      o1 = __builtin_amdgcn_mfma_f32_16x16x32_bf16(pa, vb1, o1, 0, 0, 0);
    }
    __syncthreads();
  }

  #pragma unroll
  for (int r=0;r<4;r++){
    float rl = 1.f / lrow[r];
    int qr = wid*16 + g*4 + r;
    if (qr < 49){
      bf16* op = obuf + ((size_t)w*49 + qr)*256 + hh*32;
      op[li]      = f2bf(o0[r]*rl);
      op[16 + li] = f2bf(o1[r]*rl);
    }
  }
}

// ---------------- K4: MFMA out-proj + shortcut + ls1 + window-reverse ------
// 324 blocks (one per window), 4 waves. Wave owns out-cols [wid*64, +64).
__global__ __launch_bounds__(256) void proj_kernel(
    const bf16* __restrict__ obuf, const float* __restrict__ x,
    const bf16* __restrict__ PWF, const float* __restrict__ proj_b,
    const float* __restrict__ ls1, float* __restrict__ xobuf){
  __shared__ __align__(16) unsigned short on[64*256];  // swizzled bf16, 32 KB
  int tid = threadIdx.x, wid = tid>>6, lane = tid&63;
  int li = lane&15, lg = lane>>4;
  int w = blockIdx.x;
  int b = w/81, wi = w - b*81, wh = wi/9, ww = wi - wh*9;
  const bf16* ob = obuf + (size_t)w*49*256;
  // stage O window (49 rows, pad to 64 with zeros), XOR-swizzled
  for (int c=tid; c<2048; c+=256){
    int row = c>>5, col8 = (c&31)*8;
    int idx = (row*256 + col8) ^ ((row&7)<<3);
    uint4 v = make_uint4(0,0,0,0);
    if (row < 49) v = *(const uint4*)(ob + row*256 + col8);
    *(uint4*)&on[idx] = v;
  }
  float pbv[4], l1v[4];
  #pragma unroll
  for (int nt=0; nt<4; nt++){
    int col = wid*64 + nt*16 + li;
    pbv[nt] = proj_b[col];
    l1v[nt] = ls1[col];
  }
  __syncthreads();
  for (int rt=0; rt<4; rt++){
    bf16x8 a[8];
    #pragma unroll
    for (int ks=0; ks<8; ks++){
      int idx = ((rt*16+li)*256 + ks*32 + lg*8) ^ ((li&7)<<3);
      a[ks] = *(const bf16x8*)&on[idx];
    }
    #pragma unroll
    for (int nt=0; nt<4; nt++){
      int nt2 = wid*4 + nt;
      const bf16* wp = PWF + (size_t)nt2*4096 + lane*8;
      f32x4 acc = {0.f,0.f,0.f,0.f};
      #pragma unroll
      for (int ks=0; ks<8; ks++){
        bf16x8 bfrag = *(const bf16x8*)(wp + ks*512);
        acc = __builtin_amdgcn_mfma_f32_16x16x32_bf16(a[ks], bfrag, acc, 0, 0, 0);
      }
      int col = wid*64 + nt*16 + li;
      #pragma unroll
      for (int r=0; r<4; r++){
        int t = rt*16 + lg*4 + r;
        if (t < 49){
          int rr = t/7, cc = t - rr*7;
          int gh = wh*7 + rr, gw = ww*7 + cc;
          if (gh < 60 && gw < 60){
            size_t p = (size_t)(b*3600 + gh*60 + gw)*256 + col;
            xobuf[p] = x[p] + l1v[nt]*(acc[r] + pbv[nt]);
          }
        }
      }
    }
  }
}

// ---------------- K5: MFMA MLP: LN + fc1 + GELU + fc2 + residual -----------
// 450 blocks x 32 tokens, 256 threads (4 waves). Wave owns 64-col slices.
// B-frags: coalesced 1KB wave-loads from fragment-packed L2-resident weights.
__global__ __launch_bounds__(256) void mlp_kernel(
    const float* __restrict__ xobuf, const float* __restrict__ g,
    const float* __restrict__ bb, const bf16* __restrict__ W1F,
    const float* __restrict__ fc1_b, const bf16* __restrict__ W2F,
    const float* __restrict__ fc2_b, const float* __restrict__ ls2,
    float* __restrict__ out){
  __shared__ __align__(16) unsigned short xn[32*256];  // swizzled bf16, 16 KB
  __shared__ __align__(16) unsigned short Hls[32*256]; // swizzled bf16, 16 KB
  int tid = threadIdx.x, wid = tid>>6, lane = tid&63;
  int li = lane&15, lg = lane>>4;
  int tok0 = blockIdx.x * 32;
  // ---- LN of 32 tokens -> xn (bf16, XOR-swizzled rows); 8 tokens/wave ----
  {
    float4 g4 = ((const float4*)g)[lane];
    float4 b4 = ((const float4*)bb)[lane];
    #pragma unroll
    for (int tt=0; tt<8; tt++){
      int t = wid*8 + tt;
      float4 v = ((const float4*)(xobuf + (size_t)(tok0+t)*256))[lane];
      float s = v.x+v.y+v.z+v.w;
      float ss = v.x*v.x+v.y*v.y+v.z*v.z+v.w*v.w;
      #pragma unroll
      for (int off=32; off; off>>=1){ s += __shfl_xor(s,off); ss += __shfl_xor(ss,off); }
      float mean = s*(1.f/256.f);
      float var = fmaxf(ss*(1.f/256.f)-mean*mean, 0.f);
      float inv = rsqrtf(var+1e-5f);
      ushort4 pk;
      pk.x = f2bfu((v.x-mean)*inv*g4.x+b4.x);
      pk.y = f2bfu((v.y-mean)*inv*g4.y+b4.y);
      pk.z = f2bfu((v.z-mean)*inv*g4.z+b4.z);
      pk.w = f2bfu((v.w-mean)*inv*g4.w+b4.w);
      int idx = (t*256 + lane*4) ^ ((t&7)<<3);
      *(ushort4*)&xn[idx] = pk;
    }
  }
  __syncthreads();
  // ---- A-frags for fc1: 2 row-tiles x 8 k-chunks ----
  bf16x8 a1[2][8];
  #pragma unroll
  for (int rt=0; rt<2; rt++){
    #pragma unroll
    for (int ks=0; ks<8; ks++){
      int idx = ((rt*16+li)*256 + ks*32 + lg*8) ^ ((li&7)<<3);
      a1[rt][ks] = *(const bf16x8*)&xn[idx];
    }
  }
  f32x4 oacc[2][4];
  #pragma unroll
  for (int rt=0; rt<2; rt++)
    #pragma unroll
    for (int nt=0; nt<4; nt++) oacc[rt][nt] = (f32x4){0.f,0.f,0.f,0.f};

  for (int j=0; j<4; j++){
    // fc1 + GELU -> Hls (wave's 64-col slice of the 256-col j-tile)
    #pragma unroll
    for (int nn=0; nn<4; nn++){
      int ntg = j*16 + wid*4 + nn;                 // global 16-col tile of 1024
      const bf16* wp = W1F + (size_t)ntg*4096 + lane*8;
      f32x4 hc0 = {0.f,0.f,0.f,0.f}, hc1 = {0.f,0.f,0.f,0.f};
      #pragma unroll
      for (int ks=0; ks<8; ks++){
        bf16x8 bfrag = *(const bf16x8*)(wp + ks*512);
        hc0 = __builtin_amdgcn_mfma_f32_16x16x32_bf16(a1[0][ks], bfrag, hc0, 0, 0, 0);
        hc1 = __builtin_amdgcn_mfma_f32_16x16x32_bf16(a1[1][ks], bfrag, hc1, 0, 0, 0);
      }
      float bias = fc1_b[ntg*16 + li];
      int colLoc = wid*64 + nn*16 + li;
      #pragma unroll
      for (int rt=0; rt<2; rt++){
        #pragma unroll
        for (int r=0; r<4; r++){
          float h = (rt ? hc1[r] : hc0[r]) + bias;
          float z = 0.7978845608f*(h + 0.044715f*h*h*h);   // tanh-approx GELU
          z = fminf(fmaxf(z, -15.f), 15.f);
          float e = __expf(2.f*z);
          float gv = 0.5f*h*(1.f + (e-1.f)/(e+1.f));
          int row = rt*16 + lg*4 + r;
          int idx = (row*256 + colLoc) ^ ((row&7)<<3);
          Hls[idx] = f2bfu(gv);
        }
      }
    }
    __syncthreads();
    // fc2: oacc += H(32x256 j-slice) x W2F
    bf16x8 a2[2][8];
    #pragma unroll
    for (int rt=0; rt<2; rt++){
      #pragma unroll
      for (int ks=0; ks<8; ks++){
        int idx = ((rt*16+li)*256 + ks*32 + lg*8) ^ ((li&7)<<3);
        a2[rt][ks] = *(const bf16x8*)&Hls[idx];
      }
    }
    #pragma unroll
    for (int nt=0; nt<4; nt++){
      int nt2 = wid*4 + nt;
      const bf16* wp2 = W2F + ((size_t)nt2*32 + j*8)*512 + lane*8;
      #pragma unroll
      for (int ks=0; ks<8; ks++){
        bf16x8 bfrag = *(const bf16x8*)(wp2 + ks*512);
        oacc[0][nt] = __builtin_amdgcn_mfma_f32_16x16x32_bf16(a2[0][ks], bfrag, oacc[0][nt], 0, 0, 0);
        oacc[1][nt] = __builtin_amdgcn_mfma_f32_16x16x32_bf16(a2[1][ks], bfrag, oacc[1][nt], 0, 0, 0);
      }
    }
    __syncthreads();
  }
  // ---- epilogue: residual + ls2 ----
  #pragma unroll
  for (int nt=0; nt<4; nt++){
    int col = wid*64 + nt*16 + li;
    float l2 = ls2[col];
    float cb = fc2_b[col];
    #pragma unroll
    for (int rt=0; rt<2; rt++){
      #pragma unroll
      for (int r=0; r<4; r++){
        int tok = tok0 + rt*16 + lg*4 + r;
        size_t p = (size_t)tok*256 + col;
        out[p] = xobuf[p] + l2*(oacc[rt][nt][r] + cb);
      }
    }
  }
}

extern "C" void kernel_launch(void* const* d_in, const int* in_sizes, int n_in,
                              void* d_out, int out_size, void* d_ws, size_t ws_size,
                              hipStream_t stream) {
  (void)in_sizes; (void)n_in; (void)out_size; (void)ws_size;
  const float* x      = (const float*)d_in[0];
  const float* y      = (const float*)d_in[1];
  const float* n1g    = (const float*)d_in[2];
  const float* n1b    = (const float*)d_in[3];
  const float* q_w    = (const float*)d_in[4];
  const float* kv_w   = (const float*)d_in[5];
  const float* proj_w = (const float*)d_in[6];
  const float* proj_b = (const float*)d_in[7];
  const float* n2g    = (const float*)d_in[8];
  const float* n2b    = (const float*)d_in[9];
  const float* fc1_w  = (const float*)d_in[10];
  const float* fc1_b  = (const float*)d_in[11];
  const float* fc2_w  = (const float*)d_in[12];
  const float* fc2_b  = (const float*)d_in[13];
  const float* ls1    = (const float*)d_in[14];
  const float* ls2    = (const float*)d_in[15];

  char* ws = (char*)d_ws;
  // Workspace (24.1 MB):
  //   kvbuf bf16[4*729*512]   @ 0          live K1..K3
  //   qbuf  bf16[324*49*256]  @ 2,985,984  live K2..K3
  //   obuf  bf16[324*49*256]  @ 14,745,600 live K3..K4
  //   xobuf f32 [4*3600*256]  @ 0          live K4..K5 (overlays dead kv/q)
  //   W1F   bf16[262144]      @ 22,874,112 packed fc1 (512 KB)
  //   W2F   bf16[262144]      @ 23,398,400 packed fc2 (512 KB)
  //   PWF   bf16[65536]       @ 23,922,688 packed proj (128 KB)
  bf16*  kvbuf = (bf16*)(ws);
  bf16*  qbuf  = (bf16*)(ws + 2985984);
  bf16*  obuf  = (bf16*)(ws + 14745600);
  float* xobuf = (float*)(ws);
  bf16*  W1F   = (bf16*)(ws + 22874112);
  bf16*  W2F   = (bf16*)(ws + 23398400);
  bf16*  PWF   = (bf16*)(ws + 23922688);

  wt_kernel<<<2304, 256, 0, stream>>>(fc1_w, fc2_w, proj_w, W1F, W2F, PWF);
  kv_kernel<<<729, 256, 0, stream>>>(y, n1g, n1b, kv_w, kvbuf);
  q_kernel<<<324, 256, 0, stream>>>(x, n1g, n1b, q_w, qbuf);
  attn_kernel<<<2592, 256, 0, stream>>>(qbuf, kvbuf, obuf);
  proj_kernel<<<324, 256, 0, stream>>>(obuf, x, PWF, proj_b, ls1, xobuf);
  mlp_kernel<<<450, 256, 0, stream>>>(xobuf, n2g, n2b, W1F, fc1_b, W2F, fc2_b, ls2,
                                      (float*)d_out);
}

// Round 6
// 331.909 us; speedup vs baseline: 12.0360x; 1.0015x over previous
//
#include <hip/hip_runtime.h>
#include <hip/hip_bf16.h>

typedef __hip_bfloat16 bf16;
typedef __attribute__((ext_vector_type(8))) short bf16x8;
typedef __attribute__((ext_vector_type(4))) float f32x4;

// Problem constants: B=4, H=W=60, C=256, HEADS=8, hd=32, WS=7 -> 9x9 windows/batch,
// 324 windows, 49 q/window, key window 27x27=729 gathered from the 27x27 stride-3
// grid. KEY IDENTITY: token = kk + C with C = 81*wh + 3*ww - 336 (window width ==
// grid width) -> the gather is a contiguous token slice; OOB masked by select.
// All external I/O f32; staging buffers bf16.
//
// Verified MFMA lane mapping (16x16x32 bf16, rounds 3-5):
//   A-frag: lane(li=lane&15, lg=lane>>4) holds A[row=li][k=kc*32+lg*8+e]
//   B-frag: lane holds B[col=li][k=kc*32+lg*8+e]
//   C/D   : [row=lg*4+r][col=li]

__device__ __forceinline__ bf16 f2bf(float f){ return __float2bfloat16(f); }
__device__ __forceinline__ unsigned short f2bfu(float f){
  __hip_bfloat16 h = __float2bfloat16(f);
  return *(unsigned short*)&h;
}

// ---------------- K0: pack fc1/fc2/proj weights + zero vbufT pads ----------
__global__ __launch_bounds__(256) void wt_kernel(
    const float* __restrict__ fc1_w, const float* __restrict__ fc2_w,
    const float* __restrict__ proj_w,
    bf16* __restrict__ W1F, bf16* __restrict__ W2F, bf16* __restrict__ PWF,
    bf16* __restrict__ vbufT){
  int gid = blockIdx.x*256 + threadIdx.x;
  if (gid < 262144){               // W1F: K=256 (kc<8), N=1024 (nt<64)
    int e=gid&7, lane=(gid>>3)&63, kc=(gid>>9)&7, nt=gid>>12;
    int li=lane&15, lg=lane>>4;
    W1F[gid] = f2bf(fc1_w[(size_t)(kc*32+lg*8+e)*1024 + nt*16+li]);
  } else if (gid < 524288){        // W2F: K=1024 (kc<32), N=256 (nt<16)
    int o = gid - 262144;
    int e=o&7, lane=(o>>3)&63, kc=(o>>9)&31, nt=o>>14;
    int li=lane&15, lg=lane>>4;
    W2F[o] = f2bf(fc2_w[(size_t)(kc*32+lg*8+e)*256 + nt*16+li]);
  } else if (gid < 589824){        // PWF: K=256 (kc<8), N=256 (nt<16)
    int o = gid - 524288;
    int e=o&7, lane=(o>>3)&63, kc=(o>>9)&7, nt=o>>12;
    int li=lane&15, lg=lane>>4;
    PWF[o] = f2bf(proj_w[(size_t)(kc*32+lg*8+e)*256 + nt*16+li]);
  } else {
    // zero vbufT row pads [row*736+729, +7) and hi-guard [1024*736, +512):
    // attn's OOB V reads must hit FINITE bf16 (P=0 kills the value; NaN wouldn't).
    int idx = gid - 589824;        // 0..7679
    if (idx < 7168){
      int row = idx/7, p = idx - row*7;
      vbufT[(size_t)row*736 + 729 + p] = f2bf(0.f);
    } else if (idx < 7680){
      vbufT[(size_t)1024*736 + (idx-7168)] = f2bf(0.f);
    }
  }
}

// ---------------- K1: LN(y) + kv proj -> kbuf (key-major) + vbufT (dim-major)
__global__ __launch_bounds__(256) void kv_kernel(
    const float* __restrict__ y, const float* __restrict__ g,
    const float* __restrict__ bb, const float* __restrict__ kv_w,
    bf16* __restrict__ kbuf, bf16* __restrict__ vbufT){
  __shared__ __align__(16) float xn[4*256];
  int tid = threadIdx.x, wid = tid >> 6, lane = tid & 63;
  int bs0 = blockIdx.x * 4;
  {
    int bs = bs0 + wid;
    float4 v = ((const float4*)(y + (size_t)bs*256))[lane];
    float s = v.x+v.y+v.z+v.w, ss = v.x*v.x+v.y*v.y+v.z*v.z+v.w*v.w;
    #pragma unroll
    for (int off=32; off; off>>=1){ s += __shfl_xor(s,off); ss += __shfl_xor(ss,off); }
    float mean = s*(1.f/256.f);
    float var  = fmaxf(ss*(1.f/256.f) - mean*mean, 0.f);
    float inv  = rsqrtf(var + 1e-5f);
    float4 g4 = ((const float4*)g)[lane];
    float4 b4 = ((const float4*)bb)[lane];
    float4 o;
    o.x=(v.x-mean)*inv*g4.x+b4.x;
    o.y=(v.y-mean)*inv*g4.y+b4.y;
    o.z=(v.z-mean)*inv*g4.z+b4.z;
    o.w=(v.w-mean)*inv*g4.w+b4.w;
    ((float4*)xn)[wid*64 + lane] = o;
  }
  __syncthreads();
  float acc[4][2];
  #pragma unroll
  for (int t=0;t<4;t++){ acc[t][0]=0.f; acc[t][1]=0.f; }
  for (int k4=0;k4<64;k4++){
    float xv[4][4];
    #pragma unroll
    for (int t=0;t<4;t++) *(float4*)&xv[t][0] = ((const float4*)xn)[t*64+k4];
    #pragma unroll
    for (int j=0;j<4;j++){
      int k = k4*4+j;
      float w0 = kv_w[(size_t)k*512 + tid];
      float w1 = kv_w[(size_t)k*512 + 256 + tid];
      #pragma unroll
      for (int t=0;t<4;t++){
        acc[t][0] = fmaf(xv[t][j], w0, acc[t][0]);
        acc[t][1] = fmaf(xv[t][j], w1, acc[t][1]);
      }
    }
  }
  #pragma unroll
  for (int t=0;t<4;t++){
    int gtok = bs0 + t;
    kbuf[(size_t)gtok*256 + tid] = f2bf(acc[t][0]);
    int b2 = (gtok>=729) + (gtok>=1458) + (gtok>=2187);
    int ltok = gtok - b2*729;
    vbufT[(size_t)(b2*256 + tid)*736 + ltok] = f2bf(acc[t][1]);
  }
}

// ---------------- K2: per-window LN(xw) + q projection (scale folded) ------
__global__ __launch_bounds__(256) void q_kernel(
    const float* __restrict__ x, const float* __restrict__ g,
    const float* __restrict__ bb, const float* __restrict__ q_w,
    bf16* __restrict__ qbuf){
  __shared__ __align__(16) float xn[49*256];
  int tid = threadIdx.x, wid = tid>>6, lane = tid&63;
  int w = blockIdx.x;
  int b = w/81, wi = w - b*81, wh = wi/9, ww = wi - wh*9;
  float4 g4 = ((const float4*)g)[lane];
  float4 b4 = ((const float4*)bb)[lane];
  for (int t=wid; t<49; t+=4){
    int r = t/7, c = t - r*7;
    int gh = wh*7 + r, gw = ww*7 + c;
    float4 v = make_float4(0.f,0.f,0.f,0.f);
    if (gh < 60 && gw < 60){
      v = ((const float4*)(x + (size_t)(b*3600 + gh*60 + gw)*256))[lane];
    }
    float s=v.x+v.y+v.z+v.w, ss=v.x*v.x+v.y*v.y+v.z*v.z+v.w*v.w;
    #pragma unroll
    for (int off=32; off; off>>=1){ s += __shfl_xor(s,off); ss += __shfl_xor(ss,off); }
    float mean = s*(1.f/256.f);
    float var = fmaxf(ss*(1.f/256.f)-mean*mean, 0.f);
    float inv = rsqrtf(var+1e-5f);
    float4 o;
    o.x=(v.x-mean)*inv*g4.x+b4.x;
    o.y=(v.y-mean)*inv*g4.y+b4.y;
    o.z=(v.z-mean)*inv*g4.z+b4.z;
    o.w=(v.w-mean)*inv*g4.w+b4.w;
    ((float4*)xn)[t*64 + lane] = o;
  }
  __syncthreads();
  float acc[49];
  #pragma unroll
  for (int t=0;t<49;t++) acc[t]=0.f;
  for (int k4=0;k4<64;k4++){
    float wv[4];
    #pragma unroll
    for (int j=0;j<4;j++) wv[j] = q_w[(size_t)(k4*4+j)*256 + tid];
    #pragma unroll
    for (int t=0;t<49;t++){
      float xv[4];
      *(float4*)xv = ((const float4*)xn)[t*64+k4];
      acc[t] = fmaf(xv[0],wv[0],fmaf(xv[1],wv[1],fmaf(xv[2],wv[2],fmaf(xv[3],wv[3],acc[t]))));
    }
  }
  bf16* qb = qbuf + (size_t)w*49*256 + tid;
  #pragma unroll
  for (int t=0;t<49;t++) qb[t*256] = f2bf(acc[t]*0.17677669529663689f); // hd^-0.5 folded
}

// ---------------- K3: barrier-free MFMA attention --------------------------
// block = (window, head): grid 324*8, 4 waves x 16 q-rows. K/V B-frags come
// STRAIGHT FROM GLOBAL (L2): kbuf rows / vbufT dim-major rows. Only LDS use is
// the per-wave P round-trip (16 KB). No __syncthreads anywhere.
__global__ __launch_bounds__(256) void attn_kernel(
    const bf16* __restrict__ qbuf, const bf16* __restrict__ kbuf,
    const bf16* __restrict__ vbufT, bf16* __restrict__ obuf){
  __shared__ __align__(16) unsigned short Pls[4][2048]; // per-wave P, swizzled

  int tid = threadIdx.x, wid = tid>>6, lane = tid&63;
  int g = lane>>4, li = lane&15;
  int blk = blockIdx.x;
  int w = blk >> 3, hh = blk & 7;
  int b = w/81, wi = w - b*81, wh = wi/9, ww = wi - wh*9;

  int C  = 81*wh + 3*ww - 336;     // token = kk + C
  int T0 = C & ~7, off = C & 7;    // aligned tile origin; kk = j - off
  int wh3 = wh*3 - 12, ww3 = ww*3 - 12;
  const bf16* kb = kbuf  + (long long)(b*729 + T0)*256 + hh*32;
  const bf16* vb = vbufT + (long long)(b*256 + hh*32)*736 + T0;

  bf16x8 qa;
  #pragma unroll
  for (int e=0;e<8;e++) qa[e]=0;
  int qrow = wid*16 + li;
  if (qrow < 49){
    qa = *(const bf16x8*)(qbuf + ((size_t)w*49+qrow)*256 + hh*32 + g*8);
  }

  f32x4 o0 = {0.f,0.f,0.f,0.f}, o1 = {0.f,0.f,0.f,0.f};
  float mrow[4], lrow[4];
  #pragma unroll
  for (int r=0;r<4;r++){ mrow[r] = -3.0e38f; lrow[r] = 0.f; }

  for (int tile=0; tile<6; tile++){
    int jbase = tile*128;
    // ---- S = Q K^T, B-frags direct from kbuf ----
    f32x4 s[8];
    #pragma unroll
    for (int t=0;t<8;t++){
      bf16x8 kf = *(const bf16x8*)(kb + (long long)(jbase + t*16 + li)*256 + g*8);
      f32x4 z = {0.f,0.f,0.f,0.f};
      s[t] = __builtin_amdgcn_mfma_f32_16x16x32_bf16(qa, kf, z, 0, 0, 0);
    }
    // ---- validity SELECT (not add): garbage K from OOB reads is discarded ----
    #pragma unroll
    for (int t=0;t<8;t++){
      int kk = jbase + t*16 + li - off;
      int kr = (kk*2428)>>16;            // exact /27 for 0<=kk<3276
      int kc = kk - kr*27;
      int gr = wh3 + kr, gc = ww3 + kc;
      bool valid = ((unsigned)kk < 729u) && ((unsigned)gr < 27u) &&
                   ((unsigned)gc < 27u) && !(gr >= 24 && gc >= 24);
      #pragma unroll
      for (int r=0;r<4;r++) s[t][r] = valid ? s[t][r] : -30000.f;
    }
    // ---- online softmax (rows = g*4+r, cols spread over li & t) ----
    float fac[4], ps[4];
    #pragma unroll
    for (int r=0;r<4;r++){
      float mt = s[0][r];
      #pragma unroll
      for (int t=1;t<8;t++) mt = fmaxf(mt, s[t][r]);
      mt = fmaxf(mt, __shfl_xor(mt, 1));
      mt = fmaxf(mt, __shfl_xor(mt, 2));
      mt = fmaxf(mt, __shfl_xor(mt, 4));
      mt = fmaxf(mt, __shfl_xor(mt, 8));
      float mn = fmaxf(mrow[r], mt);
      fac[r] = __expf(mrow[r] - mn);
      mrow[r] = mn;
      ps[r] = 0.f;
    }
    #pragma unroll
    for (int t=0;t<8;t++){
      #pragma unroll
      for (int r=0;r<4;r++){
        float p = __expf(s[t][r] - mrow[r]);
        s[t][r] = p;
        ps[r] += p;
      }
    }
    #pragma unroll
    for (int r=0;r<4;r++){
      ps[r] += __shfl_xor(ps[r], 1);
      ps[r] += __shfl_xor(ps[r], 2);
      ps[r] += __shfl_xor(ps[r], 4);
      ps[r] += __shfl_xor(ps[r], 8);
      lrow[r] = lrow[r]*fac[r] + ps[r];
      o0[r] *= fac[r];
      o1[r] *= fac[r];
    }
    // ---- P -> per-wave LDS (bf16, XOR-swizzled rows); wave-local, no barrier
    #pragma unroll
    for (int t=0;t<8;t++){
      #pragma unroll
      for (int r=0;r<4;r++){
        int row = g*4 + r;
        int idx = (row*128 + t*16 + li) ^ ((row&7)<<3);
        Pls[wid][idx] = f2bfu(s[t][r]);
      }
    }
    // ---- O += P V, V B-frags direct from vbufT (dim-major, 16B aligned) ----
    #pragma unroll
    for (int c=0;c<4;c++){
      int pidx = (li*128 + c*32 + g*8) ^ ((li&7)<<3);
      bf16x8 pa = *(const bf16x8*)&Pls[wid][pidx];
      const bf16* vp = vb + jbase + c*32 + g*8;
      bf16x8 vb0 = *(const bf16x8*)(vp + (long long)li*736);
      bf16x8 vb1 = *(const bf16x8*)(vp + (long long)(li+16)*736);
      o0 = __builtin_amdgcn_mfma_f32_16x16x32_bf16(pa, vb0, o0, 0, 0, 0);
      o1 = __builtin_amdgcn_mfma_f32_16x16x32_bf16(pa, vb1, o1, 0, 0, 0);
    }
  }

  // ---- epilogue: O /= l, write rows g*4+r ----
  #pragma unroll
  for (int r=0;r<4;r++){
    float rl = 1.f / lrow[r];
    int qr = wid*16 + g*4 + r;
    if (qr < 49){
      bf16* op = obuf + ((size_t)w*49 + qr)*256 + hh*32;
      op[li]      = f2bf(o0[r]*rl);
      op[16 + li] = f2bf(o1[r]*rl);
    }
  }
}

// ---------------- K4: MFMA out-proj + shortcut + ls1 + window-reverse ------
__global__ __launch_bounds__(256) void proj_kernel(
    const bf16* __restrict__ obuf, const float* __restrict__ x,
    const bf16* __restrict__ PWF, const float* __restrict__ proj_b,
    const float* __restrict__ ls1, float* __restrict__ xobuf){
  __shared__ __align__(16) unsigned short on[64*256];  // swizzled bf16, 32 KB
  int tid = threadIdx.x, wid = tid>>6, lane = tid&63;
  int li = lane&15, lg = lane>>4;
  int w = blockIdx.x;
  int b = w/81, wi = w - b*81, wh = wi/9, ww = wi - wh*9;
  const bf16* ob = obuf + (size_t)w*49*256;
  for (int c=tid; c<2048; c+=256){
    int row = c>>5, col8 = (c&31)*8;
    int idx = (row*256 + col8) ^ ((row&7)<<3);
    uint4 v = make_uint4(0,0,0,0);
    if (row < 49) v = *(const uint4*)(ob + row*256 + col8);
    *(uint4*)&on[idx] = v;
  }
  float pbv[4], l1v[4];
  #pragma unroll
  for (int nt=0; nt<4; nt++){
    int col = wid*64 + nt*16 + li;
    pbv[nt] = proj_b[col];
    l1v[nt] = ls1[col];
  }
  __syncthreads();
  for (int rt=0; rt<4; rt++){
    bf16x8 a[8];
    #pragma unroll
    for (int ks=0; ks<8; ks++){
      int idx = ((rt*16+li)*256 + ks*32 + lg*8) ^ ((li&7)<<3);
      a[ks] = *(const bf16x8*)&on[idx];
    }
    #pragma unroll
    for (int nt=0; nt<4; nt++){
      int nt2 = wid*4 + nt;
      const bf16* wp = PWF + (size_t)nt2*4096 + lane*8;
      f32x4 acc = {0.f,0.f,0.f,0.f};
      #pragma unroll
      for (int ks=0; ks<8; ks++){
        bf16x8 bfrag = *(const bf16x8*)(wp + ks*512);
        acc = __builtin_amdgcn_mfma_f32_16x16x32_bf16(a[ks], bfrag, acc, 0, 0, 0);
      }
      int col = wid*64 + nt*16 + li;
      #pragma unroll
      for (int r=0; r<4; r++){
        int t = rt*16 + lg*4 + r;
        if (t < 49){
          int rr = t/7, cc = t - rr*7;
          int gh = wh*7 + rr, gw = ww*7 + cc;
          if (gh < 60 && gw < 60){
            size_t p = (size_t)(b*3600 + gh*60 + gw)*256 + col;
            xobuf[p] = x[p] + l1v[nt]*(acc[r] + pbv[nt]);
          }
        }
      }
    }
  }
}

// ---------------- K5: MFMA MLP: LN + fc1 + GELU + fc2 + residual -----------
__global__ __launch_bounds__(256) void mlp_kernel(
    const float* __restrict__ xobuf, const float* __restrict__ g,
    const float* __restrict__ bb, const bf16* __restrict__ W1F,
    const float* __restrict__ fc1_b, const bf16* __restrict__ W2F,
    const float* __restrict__ fc2_b, const float* __restrict__ ls2,
    float* __restrict__ out){
  __shared__ __align__(16) unsigned short xn[32*256];  // swizzled bf16, 16 KB
  __shared__ __align__(16) unsigned short Hls[32*256]; // swizzled bf16, 16 KB
  int tid = threadIdx.x, wid = tid>>6, lane = tid&63;
  int li = lane&15, lg = lane>>4;
  int tok0 = blockIdx.x * 32;
  {
    float4 g4 = ((const float4*)g)[lane];
    float4 b4 = ((const float4*)bb)[lane];
    #pragma unroll
    for (int tt=0; tt<8; tt++){
      int t = wid*8 + tt;
      float4 v = ((const float4*)(xobuf + (size_t)(tok0+t)*256))[lane];
      float s = v.x+v.y+v.z+v.w;
      float ss = v.x*v.x+v.y*v.y+v.z*v.z+v.w*v.w;
      #pragma unroll
      for (int off=32; off; off>>=1){ s += __shfl_xor(s,off); ss += __shfl_xor(ss,off); }
      float mean = s*(1.f/256.f);
      float var = fmaxf(ss*(1.f/256.f)-mean*mean, 0.f);
      float inv = rsqrtf(var+1e-5f);
      ushort4 pk;
      pk.x = f2bfu((v.x-mean)*inv*g4.x+b4.x);
      pk.y = f2bfu((v.y-mean)*inv*g4.y+b4.y);
      pk.z = f2bfu((v.z-mean)*inv*g4.z+b4.z);
      pk.w = f2bfu((v.w-mean)*inv*g4.w+b4.w);
      int idx = (t*256 + lane*4) ^ ((t&7)<<3);
      *(ushort4*)&xn[idx] = pk;
    }
  }
  __syncthreads();
  bf16x8 a1[2][8];
  #pragma unroll
  for (int rt=0; rt<2; rt++){
    #pragma unroll
    for (int ks=0; ks<8; ks++){
      int idx = ((rt*16+li)*256 + ks*32 + lg*8) ^ ((li&7)<<3);
      a1[rt][ks] = *(const bf16x8*)&xn[idx];
    }
  }
  f32x4 oacc[2][4];
  #pragma unroll
  for (int rt=0; rt<2; rt++)
    #pragma unroll
    for (int nt=0; nt<4; nt++) oacc[rt][nt] = (f32x4){0.f,0.f,0.f,0.f};

  for (int j=0; j<4; j++){
    #pragma unroll
    for (int nn=0; nn<4; nn++){
      int ntg = j*16 + wid*4 + nn;
      const bf16* wp = W1F + (size_t)ntg*4096 + lane*8;
      f32x4 hc0 = {0.f,0.f,0.f,0.f}, hc1 = {0.f,0.f,0.f,0.f};
      #pragma unroll
      for (int ks=0; ks<8; ks++){
        bf16x8 bfrag = *(const bf16x8*)(wp + ks*512);
        hc0 = __builtin_amdgcn_mfma_f32_16x16x32_bf16(a1[0][ks], bfrag, hc0, 0, 0, 0);
        hc1 = __builtin_amdgcn_mfma_f32_16x16x32_bf16(a1[1][ks], bfrag, hc1, 0, 0, 0);
      }
      float bias = fc1_b[ntg*16 + li];
      int colLoc = wid*64 + nn*16 + li;
      #pragma unroll
      for (int rt=0; rt<2; rt++){
        #pragma unroll
        for (int r=0; r<4; r++){
          float h = (rt ? hc1[r] : hc0[r]) + bias;
          float z = 0.7978845608f*(h + 0.044715f*h*h*h);   // tanh-approx GELU
          z = fminf(fmaxf(z, -15.f), 15.f);
          float e = __expf(2.f*z);
          float gv = 0.5f*h*(1.f + (e-1.f)/(e+1.f));
          int row = rt*16 + lg*4 + r;
          int idx = (row*256 + colLoc) ^ ((row&7)<<3);
          Hls[idx] = f2bfu(gv);
        }
      }
    }
    __syncthreads();
    bf16x8 a2[2][8];
    #pragma unroll
    for (int rt=0; rt<2; rt++){
      #pragma unroll
      for (int ks=0; ks<8; ks++){
        int idx = ((rt*16+li)*256 + ks*32 + lg*8) ^ ((li&7)<<3);
        a2[rt][ks] = *(const bf16x8*)&Hls[idx];
      }
    }
    #pragma unroll
    for (int nt=0; nt<4; nt++){
      int nt2 = wid*4 + nt;
      const bf16* wp2 = W2F + ((size_t)nt2*32 + j*8)*512 + lane*8;
      #pragma unroll
      for (int ks=0; ks<8; ks++){
        bf16x8 bfrag = *(const bf16x8*)(wp2 + ks*512);
        oacc[0][nt] = __builtin_amdgcn_mfma_f32_16x16x32_bf16(a2[0][ks], bfrag, oacc[0][nt], 0, 0, 0);
        oacc[1][nt] = __builtin_amdgcn_mfma_f32_16x16x32_bf16(a2[1][ks], bfrag, oacc[1][nt], 0, 0, 0);
      }
    }
    __syncthreads();
  }
  #pragma unroll
  for (int nt=0; nt<4; nt++){
    int col = wid*64 + nt*16 + li;
    float l2 = ls2[col];
    float cb = fc2_b[col];
    #pragma unroll
    for (int rt=0; rt<2; rt++){
      #pragma unroll
      for (int r=0; r<4; r++){
        int tok = tok0 + rt*16 + lg*4 + r;
        size_t p = (size_t)tok*256 + col;
        out[p] = xobuf[p] + l2*(oacc[rt][nt][r] + cb);
      }
    }
  }
}

extern "C" void kernel_launch(void* const* d_in, const int* in_sizes, int n_in,
                              void* d_out, int out_size, void* d_ws, size_t ws_size,
                              hipStream_t stream) {
  (void)in_sizes; (void)n_in; (void)out_size; (void)ws_size;
  const float* x      = (const float*)d_in[0];
  const float* y      = (const float*)d_in[1];
  const float* n1g    = (const float*)d_in[2];
  const float* n1b    = (const float*)d_in[3];
  const float* q_w    = (const float*)d_in[4];
  const float* kv_w   = (const float*)d_in[5];
  const float* proj_w = (const float*)d_in[6];
  const float* proj_b = (const float*)d_in[7];
  const float* n2g    = (const float*)d_in[8];
  const float* n2b    = (const float*)d_in[9];
  const float* fc1_w  = (const float*)d_in[10];
  const float* fc1_b  = (const float*)d_in[11];
  const float* fc2_w  = (const float*)d_in[12];
  const float* fc2_b  = (const float*)d_in[13];
  const float* ls1    = (const float*)d_in[14];
  const float* ls2    = (const float*)d_in[15];

  char* ws = (char*)d_ws;
  // Workspace (24.02 MB):
  //   qbuf  bf16[324*49*256] @ 0          live K2..K3 (also K lo-guard: garbage OK)
  //   kbuf  bf16[2916*256]   @ 8,128,512  live K1..K3
  //   vbufT bf16[1024*736+512] @ 9,621,504 live K1..K3 (pads/guard zeroed by K0;
  //                                         lo-guard = kbuf tail, finite)
  //   obuf  bf16[324*49*256] @ 14,745,600 live K3..K4
  //   xobuf f32 [4*3600*256] @ 0          live K4..K5 (overlays qbuf/kbuf/vbufT)
  //   W1F/W2F/PWF            @ 22,874,112 packed weights (1.13 MB)
  bf16*  qbuf  = (bf16*)(ws);
  bf16*  kbuf  = (bf16*)(ws + 8128512);
  bf16*  vbufT = (bf16*)(ws + 9621504);
  bf16*  obuf  = (bf16*)(ws + 14745600);
  float* xobuf = (float*)(ws);
  bf16*  W1F   = (bf16*)(ws + 22874112);
  bf16*  W2F   = (bf16*)(ws + 23398400);
  bf16*  PWF   = (bf16*)(ws + 23922688);

  wt_kernel<<<2334, 256, 0, stream>>>(fc1_w, fc2_w, proj_w, W1F, W2F, PWF, vbufT);
  kv_kernel<<<729, 256, 0, stream>>>(y, n1g, n1b, kv_w, kbuf, vbufT);
  q_kernel<<<324, 256, 0, stream>>>(x, n1g, n1b, q_w, qbuf);
  attn_kernel<<<2592, 256, 0, stream>>>(qbuf, kbuf, vbufT, obuf);
  proj_kernel<<<324, 256, 0, stream>>>(obuf, x, PWF, proj_b, ls1, xobuf);
  mlp_kernel<<<450, 256, 0, stream>>>(xobuf, n2g, n2b, W1F, fc1_b, W2F, fc2_b, ls2,
                                      (float*)d_out);
}

// Round 7
// 254.934 us; speedup vs baseline: 15.6701x; 1.3019x over previous
//
#include <hip/hip_runtime.h>
#include <hip/hip_bf16.h>

typedef __hip_bfloat16 bf16;
typedef __attribute__((ext_vector_type(8))) short bf16x8;
typedef __attribute__((ext_vector_type(4))) float f32x4;

// Problem constants: B=4, H=W=60, C=256, HEADS=8, hd=32, WS=7 -> 9x9 windows/batch,
// 324 windows, 49 q/window, key window 27x27=729 gathered from the 27x27 stride-3
// grid. KEY IDENTITY: token = kk + C with C = 81*wh + 3*ww - 336 -> contiguous
// token slice; OOB masked by select. All external I/O f32; staging bf16.
// Softmax in log2 domain: q pre-scaled by hd^-0.5 * log2(e), exp via v_exp_f32.
//
// Verified MFMA lane mapping (16x16x32 bf16, rounds 3-6):
//   A-frag: lane(li=lane&15, lg=lane>>4) holds A[row=li][k=kc*32+lg*8+e]
//   B-frag: lane holds B[col=li][k=kc*32+lg*8+e]
//   C/D   : [row=lg*4+r][col=li]
// Fragment-packed weights: F[nt*4096 + kc*512 + lane*8 + e] = W[kc*32+lg*8+e][nt*16+li]

#define QSCALE 0.25505402616302864f  // (1/sqrt(32)) * log2(e)

__device__ __forceinline__ bf16 f2bf(float f){ return __float2bfloat16(f); }
__device__ __forceinline__ unsigned short f2bfu(float f){
  __hip_bfloat16 h = __float2bfloat16(f);
  return *(unsigned short*)&h;
}

// ---------------- K0: pack all weights into fragment order + zero vbufT pads
__global__ __launch_bounds__(256) void wt_kernel(
    const float* __restrict__ fc1_w, const float* __restrict__ fc2_w,
    const float* __restrict__ proj_w, const float* __restrict__ q_w,
    const float* __restrict__ kv_w,
    bf16* __restrict__ W1F, bf16* __restrict__ W2F, bf16* __restrict__ PWF,
    bf16* __restrict__ QWF, bf16* __restrict__ KVF, bf16* __restrict__ vbufT){
  int gid = blockIdx.x*256 + threadIdx.x;
  if (gid < 262144){               // W1F: K=256 (kc<8), N=1024 (nt<64)
    int e=gid&7, lane=(gid>>3)&63, kc=(gid>>9)&7, nt=gid>>12;
    int li=lane&15, lg=lane>>4;
    W1F[gid] = f2bf(fc1_w[(size_t)(kc*32+lg*8+e)*1024 + nt*16+li]);
  } else if (gid < 524288){        // W2F: K=1024 (kc<32), N=256 (nt<16)
    int o = gid - 262144;
    int e=o&7, lane=(o>>3)&63, kc=(o>>9)&31, nt=o>>14;
    int li=lane&15, lg=lane>>4;
    W2F[o] = f2bf(fc2_w[(size_t)(kc*32+lg*8+e)*256 + nt*16+li]);
  } else if (gid < 589824){        // PWF: K=256 (kc<8), N=256 (nt<16)
    int o = gid - 524288;
    int e=o&7, lane=(o>>3)&63, kc=(o>>9)&7, nt=o>>12;
    int li=lane&15, lg=lane>>4;
    PWF[o] = f2bf(proj_w[(size_t)(kc*32+lg*8+e)*256 + nt*16+li]);
  } else if (gid < 655360){        // QWF: K=256 (kc<8), N=256 (nt<16), scaled
    int o = gid - 589824;
    int e=o&7, lane=(o>>3)&63, kc=(o>>9)&7, nt=o>>12;
    int li=lane&15, lg=lane>>4;
    QWF[o] = f2bf(q_w[(size_t)(kc*32+lg*8+e)*256 + nt*16+li] * QSCALE);
  } else if (gid < 786432){        // KVF: K=256 (kc<8), N=512 (nt<32)
    int o = gid - 655360;
    int e=o&7, lane=(o>>3)&63, kc=(o>>9)&7, nt=o>>12;
    int li=lane&15, lg=lane>>4;
    KVF[o] = f2bf(kv_w[(size_t)(kc*32+lg*8+e)*512 + nt*16+li]);
  } else {
    // zero vbufT row pads [row*736+729, +7) and hi-guard [1024*736, +512):
    // attn's OOB V reads must hit FINITE bf16 (P=0 kills the value).
    int idx = gid - 786432;        // 0..7679
    if (idx < 7168){
      int row = idx/7, p = idx - row*7;
      vbufT[(size_t)row*736 + 729 + p] = f2bf(0.f);
    } else if (idx < 7680){
      vbufT[(size_t)1024*736 + (idx-7168)] = f2bf(0.f);
    }
  }
}

// ---------------- K1: MFMA LN(y)+kv proj -> kbuf (key-major) + vbufT (dim-major)
// 183 blocks x 16 tokens, 4 waves; wave owns 128 of 512 out-cols.
__global__ __launch_bounds__(256) void kv_kernel(
    const float* __restrict__ y, const float* __restrict__ g,
    const float* __restrict__ bb, const bf16* __restrict__ KVF,
    bf16* __restrict__ kbuf, bf16* __restrict__ vbufT){
  __shared__ __align__(16) unsigned short xn[16*256];  // swizzled bf16, 8 KB
  int tid = threadIdx.x, wid = tid>>6, lane = tid&63;
  int li = lane&15, lg = lane>>4;
  int tok0 = blockIdx.x * 16;
  {
    float4 g4 = ((const float4*)g)[lane];
    float4 b4 = ((const float4*)bb)[lane];
    #pragma unroll
    for (int tt=0; tt<4; tt++){
      int t = wid*4 + tt;
      int gtok = tok0 + t;
      float4 v = make_float4(0.f,0.f,0.f,0.f);
      if (gtok < 2916) v = ((const float4*)(y + (size_t)gtok*256))[lane];
      float s = v.x+v.y+v.z+v.w, ss = v.x*v.x+v.y*v.y+v.z*v.z+v.w*v.w;
      #pragma unroll
      for (int off=32; off; off>>=1){ s += __shfl_xor(s,off); ss += __shfl_xor(ss,off); }
      float mean = s*(1.f/256.f);
      float var  = fmaxf(ss*(1.f/256.f) - mean*mean, 0.f);
      float inv  = rsqrtf(var + 1e-5f);
      ushort4 pk;
      pk.x = f2bfu((v.x-mean)*inv*g4.x+b4.x);
      pk.y = f2bfu((v.y-mean)*inv*g4.y+b4.y);
      pk.z = f2bfu((v.z-mean)*inv*g4.z+b4.z);
      pk.w = f2bfu((v.w-mean)*inv*g4.w+b4.w);
      int idx = (t*256 + lane*4) ^ ((t&7)<<3);
      *(ushort4*)&xn[idx] = pk;
    }
  }
  __syncthreads();
  bf16x8 a[8];
  #pragma unroll
  for (int ks=0; ks<8; ks++){
    int idx = (li*256 + ks*32 + lg*8) ^ ((li&7)<<3);
    a[ks] = *(const bf16x8*)&xn[idx];
  }
  #pragma unroll
  for (int nn=0; nn<8; nn++){
    int ntg = wid*8 + nn;
    const bf16* wp = KVF + (size_t)ntg*4096 + lane*8;
    f32x4 acc = {0.f,0.f,0.f,0.f};
    #pragma unroll
    for (int ks=0; ks<8; ks++){
      bf16x8 bfrag = *(const bf16x8*)(wp + ks*512);
      acc = __builtin_amdgcn_mfma_f32_16x16x32_bf16(a[ks], bfrag, acc, 0, 0, 0);
    }
    int col = ntg*16 + li;
    #pragma unroll
    for (int r=0; r<4; r++){
      int tok = tok0 + lg*4 + r;
      if (tok < 2916){
        if (col < 256){
          kbuf[(size_t)tok*256 + col] = f2bf(acc[r]);
        } else {
          int b2 = (tok>=729) + (tok>=1458) + (tok>=2187);
          int ltok = tok - b2*729;
          vbufT[(size_t)(b2*256 + col-256)*736 + ltok] = f2bf(acc[r]);
        }
      }
    }
  }
}

// ---------------- K2: MFMA per-window LN(xw)+q proj (scale in QWF) ---------
// 324 blocks, 4 waves; wave owns 64 out-cols; 64-row padded token tile.
__global__ __launch_bounds__(256) void q_kernel(
    const float* __restrict__ x, const float* __restrict__ g,
    const float* __restrict__ bb, const bf16* __restrict__ QWF,
    bf16* __restrict__ qbuf){
  __shared__ __align__(16) unsigned short on[64*256];  // swizzled bf16, 32 KB
  int tid = threadIdx.x, wid = tid>>6, lane = tid&63;
  int li = lane&15, lg = lane>>4;
  int w = blockIdx.x;
  int b = w/81, wi = w - b*81, wh = wi/9, ww = wi - wh*9;
  float4 g4 = ((const float4*)g)[lane];
  float4 b4 = ((const float4*)bb)[lane];
  for (int t=wid; t<64; t+=4){
    float4 v = make_float4(0.f,0.f,0.f,0.f);
    if (t < 49){
      int r = t/7, c = t - r*7;
      int gh = wh*7 + r, gw = ww*7 + c;
      if (gh < 60 && gw < 60)
        v = ((const float4*)(x + (size_t)(b*3600 + gh*60 + gw)*256))[lane];
    }
    float s=v.x+v.y+v.z+v.w, ss=v.x*v.x+v.y*v.y+v.z*v.z+v.w*v.w;
    #pragma unroll
    for (int off=32; off; off>>=1){ s += __shfl_xor(s,off); ss += __shfl_xor(ss,off); }
    float mean = s*(1.f/256.f);
    float var = fmaxf(ss*(1.f/256.f)-mean*mean, 0.f);
    float inv = rsqrtf(var+1e-5f);
    ushort4 pk;
    pk.x = f2bfu((v.x-mean)*inv*g4.x+b4.x);
    pk.y = f2bfu((v.y-mean)*inv*g4.y+b4.y);
    pk.z = f2bfu((v.z-mean)*inv*g4.z+b4.z);
    pk.w = f2bfu((v.w-mean)*inv*g4.w+b4.w);
    int idx = (t*256 + lane*4) ^ ((t&7)<<3);
    *(ushort4*)&on[idx] = pk;
  }
  __syncthreads();
  for (int rt=0; rt<4; rt++){
    bf16x8 a[8];
    #pragma unroll
    for (int ks=0; ks<8; ks++){
      int idx = ((rt*16+li)*256 + ks*32 + lg*8) ^ ((li&7)<<3);
      a[ks] = *(const bf16x8*)&on[idx];
    }
    #pragma unroll
    for (int nt=0; nt<4; nt++){
      int ntg = wid*4 + nt;
      const bf16* wp = QWF + (size_t)ntg*4096 + lane*8;
      f32x4 acc = {0.f,0.f,0.f,0.f};
      #pragma unroll
      for (int ks=0; ks<8; ks++){
        bf16x8 bfrag = *(const bf16x8*)(wp + ks*512);
        acc = __builtin_amdgcn_mfma_f32_16x16x32_bf16(a[ks], bfrag, acc, 0, 0, 0);
      }
      int col = ntg*16 + li;
      #pragma unroll
      for (int r=0; r<4; r++){
        int tok = rt*16 + lg*4 + r;
        if (tok < 49)
          qbuf[((size_t)w*49 + tok)*256 + col] = f2bf(acc[r]);
      }
    }
  }
}

// ---------------- K3: barrier-free MFMA attention, K-prefetch + V-hoist ----
__global__ __launch_bounds__(256) void attn_kernel(
    const bf16* __restrict__ qbuf, const bf16* __restrict__ kbuf,
    const bf16* __restrict__ vbufT, bf16* __restrict__ obuf){
  __shared__ __align__(16) unsigned short Pls[4][2048]; // per-wave P, swizzled

  int tid = threadIdx.x, wid = tid>>6, lane = tid&63;
  int g = lane>>4, li = lane&15;
  int blk = blockIdx.x;
  int w = blk >> 3, hh = blk & 7;
  int b = w/81, wi = w - b*81, wh = wi/9, ww = wi - wh*9;

  int C  = 81*wh + 3*ww - 336;     // token = kk + C
  int T0 = C & ~7, off = C & 7;
  int wh3 = wh*3 - 12, ww3 = ww*3 - 12;
  const bf16* kb = kbuf  + (long long)(b*729 + T0)*256 + hh*32;
  const bf16* vb = vbufT + (long long)(b*256 + hh*32)*736 + T0;

  bf16x8 qa;
  #pragma unroll
  for (int e=0;e<8;e++) qa[e]=0;
  int qrow = wid*16 + li;
  if (qrow < 49){
    qa = *(const bf16x8*)(qbuf + ((size_t)w*49+qrow)*256 + hh*32 + g*8);
  }

  f32x4 o0 = {0.f,0.f,0.f,0.f}, o1 = {0.f,0.f,0.f,0.f};
  float mrow[4], lrow[4];
  #pragma unroll
  for (int r=0;r<4;r++){ mrow[r] = -3.0e38f; lrow[r] = 0.f; }

  // K fragments for tile 0
  bf16x8 kf[8];
  #pragma unroll
  for (int t=0;t<8;t++)
    kf[t] = *(const bf16x8*)(kb + (long long)(t*16 + li)*256 + g*8);

  for (int tile=0; tile<6; tile++){
    int jbase = tile*128;
    // ---- V fragments for this tile: issue early (in flight during softmax) ----
    bf16x8 vf0[4], vf1[4];
    #pragma unroll
    for (int c=0;c<4;c++){
      const bf16* vp = vb + jbase + c*32 + g*8;
      vf0[c] = *(const bf16x8*)(vp + (long long)li*736);
      vf1[c] = *(const bf16x8*)(vp + (long long)(li+16)*736);
    }
    // ---- S = Q K^T from prefetched frags ----
    f32x4 s[8];
    #pragma unroll
    for (int t=0;t<8;t++){
      f32x4 z = {0.f,0.f,0.f,0.f};
      s[t] = __builtin_amdgcn_mfma_f32_16x16x32_bf16(qa, kf[t], z, 0, 0, 0);
    }
    // ---- prefetch K for next tile (hides L2 latency under softmax) ----
    if (tile < 5){
      #pragma unroll
      for (int t=0;t<8;t++)
        kf[t] = *(const bf16x8*)(kb + (long long)(jbase+128 + t*16 + li)*256 + g*8);
    }
    // ---- validity SELECT (garbage K discarded) ----
    #pragma unroll
    for (int t=0;t<8;t++){
      int kk = jbase + t*16 + li - off;
      int kr = (kk*2428)>>16;            // exact /27 for 0<=kk<3276
      int kc = kk - kr*27;
      int gr = wh3 + kr, gc = ww3 + kc;
      bool valid = ((unsigned)kk < 729u) && ((unsigned)gr < 27u) &&
                   ((unsigned)gc < 27u) && !(gr >= 24 && gc >= 24);
      #pragma unroll
      for (int r=0;r<4;r++) s[t][r] = valid ? s[t][r] : -30000.f;
    }
    // ---- online softmax in log2 domain ----
    float fac[4], ps[4];
    #pragma unroll
    for (int r=0;r<4;r++){
      float mt = s[0][r];
      #pragma unroll
      for (int t=1;t<8;t++) mt = fmaxf(mt, s[t][r]);
      mt = fmaxf(mt, __shfl_xor(mt, 1));
      mt = fmaxf(mt, __shfl_xor(mt, 2));
      mt = fmaxf(mt, __shfl_xor(mt, 4));
      mt = fmaxf(mt, __shfl_xor(mt, 8));
      float mn = fmaxf(mrow[r], mt);
      fac[r] = exp2f(mrow[r] - mn);
      mrow[r] = mn;
      ps[r] = 0.f;
    }
    #pragma unroll
    for (int t=0;t<8;t++){
      #pragma unroll
      for (int r=0;r<4;r++){
        float p = exp2f(s[t][r] - mrow[r]);
        s[t][r] = p;
        ps[r] += p;
      }
    }
    #pragma unroll
    for (int r=0;r<4;r++){
      ps[r] += __shfl_xor(ps[r], 1);
      ps[r] += __shfl_xor(ps[r], 2);
      ps[r] += __shfl_xor(ps[r], 4);
      ps[r] += __shfl_xor(ps[r], 8);
      lrow[r] = lrow[r]*fac[r] + ps[r];
      o0[r] *= fac[r];
      o1[r] *= fac[r];
    }
    // ---- P -> per-wave LDS (bf16, XOR-swizzled rows) ----
    #pragma unroll
    for (int t=0;t<8;t++){
      #pragma unroll
      for (int r=0;r<4;r++){
        int row = g*4 + r;
        int idx = (row*128 + t*16 + li) ^ ((row&7)<<3);
        Pls[wid][idx] = f2bfu(s[t][r]);
      }
    }
    // ---- O += P V with pre-loaded V fragments ----
    #pragma unroll
    for (int c=0;c<4;c++){
      int pidx = (li*128 + c*32 + g*8) ^ ((li&7)<<3);
      bf16x8 pa = *(const bf16x8*)&Pls[wid][pidx];
      o0 = __builtin_amdgcn_mfma_f32_16x16x32_bf16(pa, vf0[c], o0, 0, 0, 0);
      o1 = __builtin_amdgcn_mfma_f32_16x16x32_bf16(pa, vf1[c], o1, 0, 0, 0);
    }
  }

  #pragma unroll
  for (int r=0;r<4;r++){
    float rl = 1.f / lrow[r];
    int qr = wid*16 + g*4 + r;
    if (qr < 49){
      bf16* op = obuf + ((size_t)w*49 + qr)*256 + hh*32;
      op[li]      = f2bf(o0[r]*rl);
      op[16 + li] = f2bf(o1[r]*rl);
    }
  }
}

// ---------------- K4: MFMA out-proj + shortcut + ls1 + window-reverse ------
__global__ __launch_bounds__(256) void proj_kernel(
    const bf16* __restrict__ obuf, const float* __restrict__ x,
    const bf16* __restrict__ PWF, const float* __restrict__ proj_b,
    const float* __restrict__ ls1, float* __restrict__ xobuf){
  __shared__ __align__(16) unsigned short on[64*256];  // swizzled bf16, 32 KB
  int tid = threadIdx.x, wid = tid>>6, lane = tid&63;
  int li = lane&15, lg = lane>>4;
  int w = blockIdx.x;
  int b = w/81, wi = w - b*81, wh = wi/9, ww = wi - wh*9;
  const bf16* ob = obuf + (size_t)w*49*256;
  for (int c=tid; c<2048; c+=256){
    int row = c>>5, col8 = (c&31)*8;
    int idx = (row*256 + col8) ^ ((row&7)<<3);
    uint4 v = make_uint4(0,0,0,0);
    if (row < 49) v = *(const uint4*)(ob + row*256 + col8);
    *(uint4*)&on[idx] = v;
  }
  float pbv[4], l1v[4];
  #pragma unroll
  for (int nt=0; nt<4; nt++){
    int col = wid*64 + nt*16 + li;
    pbv[nt] = proj_b[col];
    l1v[nt] = ls1[col];
  }
  __syncthreads();
  for (int rt=0; rt<4; rt++){
    bf16x8 a[8];
    #pragma unroll
    for (int ks=0; ks<8; ks++){
      int idx = ((rt*16+li)*256 + ks*32 + lg*8) ^ ((li&7)<<3);
      a[ks] = *(const bf16x8*)&on[idx];
    }
    #pragma unroll
    for (int nt=0; nt<4; nt++){
      int nt2 = wid*4 + nt;
      const bf16* wp = PWF + (size_t)nt2*4096 + lane*8;
      f32x4 acc = {0.f,0.f,0.f,0.f};
      #pragma unroll
      for (int ks=0; ks<8; ks++){
        bf16x8 bfrag = *(const bf16x8*)(wp + ks*512);
        acc = __builtin_amdgcn_mfma_f32_16x16x32_bf16(a[ks], bfrag, acc, 0, 0, 0);
      }
      int col = wid*64 + nt*16 + li;
      #pragma unroll
      for (int r=0; r<4; r++){
        int t = rt*16 + lg*4 + r;
        if (t < 49){
          int rr = t/7, cc = t - rr*7;
          int gh = wh*7 + rr, gw = ww*7 + cc;
          if (gh < 60 && gw < 60){
            size_t p = (size_t)(b*3600 + gh*60 + gw)*256 + col;
            xobuf[p] = x[p] + l1v[nt]*(acc[r] + pbv[nt]);
          }
        }
      }
    }
  }
}

// ---------------- K5: MFMA MLP: LN + fc1 + GELU + fc2 + residual -----------
__global__ __launch_bounds__(256) void mlp_kernel(
    const float* __restrict__ xobuf, const float* __restrict__ g,
    const float* __restrict__ bb, const bf16* __restrict__ W1F,
    const float* __restrict__ fc1_b, const bf16* __restrict__ W2F,
    const float* __restrict__ fc2_b, const float* __restrict__ ls2,
    float* __restrict__ out){
  __shared__ __align__(16) unsigned short xn[32*256];  // swizzled bf16, 16 KB
  __shared__ __align__(16) unsigned short Hls[32*256]; // swizzled bf16, 16 KB
  int tid = threadIdx.x, wid = tid>>6, lane = tid&63;
  int li = lane&15, lg = lane>>4;
  int tok0 = blockIdx.x * 32;
  {
    float4 g4 = ((const float4*)g)[lane];
    float4 b4 = ((const float4*)bb)[lane];
    #pragma unroll
    for (int tt=0; tt<8; tt++){
      int t = wid*8 + tt;
      float4 v = ((const float4*)(xobuf + (size_t)(tok0+t)*256))[lane];
      float s = v.x+v.y+v.z+v.w;
      float ss = v.x*v.x+v.y*v.y+v.z*v.z+v.w*v.w;
      #pragma unroll
      for (int off=32; off; off>>=1){ s += __shfl_xor(s,off); ss += __shfl_xor(ss,off); }
      float mean = s*(1.f/256.f);
      float var = fmaxf(ss*(1.f/256.f)-mean*mean, 0.f);
      float inv = rsqrtf(var+1e-5f);
      ushort4 pk;
      pk.x = f2bfu((v.x-mean)*inv*g4.x+b4.x);
      pk.y = f2bfu((v.y-mean)*inv*g4.y+b4.y);
      pk.z = f2bfu((v.z-mean)*inv*g4.z+b4.z);
      pk.w = f2bfu((v.w-mean)*inv*g4.w+b4.w);
      int idx = (t*256 + lane*4) ^ ((t&7)<<3);
      *(ushort4*)&xn[idx] = pk;
    }
  }
  __syncthreads();
  bf16x8 a1[2][8];
  #pragma unroll
  for (int rt=0; rt<2; rt++){
    #pragma unroll
    for (int ks=0; ks<8; ks++){
      int idx = ((rt*16+li)*256 + ks*32 + lg*8) ^ ((li&7)<<3);
      a1[rt][ks] = *(const bf16x8*)&xn[idx];
    }
  }
  f32x4 oacc[2][4];
  #pragma unroll
  for (int rt=0; rt<2; rt++)
    #pragma unroll
    for (int nt=0; nt<4; nt++) oacc[rt][nt] = (f32x4){0.f,0.f,0.f,0.f};

  for (int j=0; j<4; j++){
    #pragma unroll
    for (int nn=0; nn<4; nn++){
      int ntg = j*16 + wid*4 + nn;
      const bf16* wp = W1F + (size_t)ntg*4096 + lane*8;
      f32x4 hc0 = {0.f,0.f,0.f,0.f}, hc1 = {0.f,0.f,0.f,0.f};
      #pragma unroll
      for (int ks=0; ks<8; ks++){
        bf16x8 bfrag = *(const bf16x8*)(wp + ks*512);
        hc0 = __builtin_amdgcn_mfma_f32_16x16x32_bf16(a1[0][ks], bfrag, hc0, 0, 0, 0);
        hc1 = __builtin_amdgcn_mfma_f32_16x16x32_bf16(a1[1][ks], bfrag, hc1, 0, 0, 0);
      }
      float bias = fc1_b[ntg*16 + li];
      int colLoc = wid*64 + nn*16 + li;
      #pragma unroll
      for (int rt=0; rt<2; rt++){
        #pragma unroll
        for (int r=0; r<4; r++){
          float h = (rt ? hc1[r] : hc0[r]) + bias;
          float z = 0.7978845608f*(h + 0.044715f*h*h*h);   // tanh-approx GELU
          z = fminf(fmaxf(z, -15.f), 15.f);
          float e = __expf(2.f*z);
          float gv = 0.5f*h*(1.f + (e-1.f)/(e+1.f));
          int row = rt*16 + lg*4 + r;
          int idx = (row*256 + colLoc) ^ ((row&7)<<3);
          Hls[idx] = f2bfu(gv);
        }
      }
    }
    __syncthreads();
    bf16x8 a2[2][8];
    #pragma unroll
    for (int rt=0; rt<2; rt++){
      #pragma unroll
      for (int ks=0; ks<8; ks++){
        int idx = ((rt*16+li)*256 + ks*32 + lg*8) ^ ((li&7)<<3);
        a2[rt][ks] = *(const bf16x8*)&Hls[idx];
      }
    }
    #pragma unroll
    for (int nt=0; nt<4; nt++){
      int nt2 = wid*4 + nt;
      const bf16* wp2 = W2F + ((size_t)nt2*32 + j*8)*512 + lane*8;
      #pragma unroll
      for (int ks=0; ks<8; ks++){
        bf16x8 bfrag = *(const bf16x8*)(wp2 + ks*512);
        oacc[0][nt] = __builtin_amdgcn_mfma_f32_16x16x32_bf16(a2[0][ks], bfrag, oacc[0][nt], 0, 0, 0);
        oacc[1][nt] = __builtin_amdgcn_mfma_f32_16x16x32_bf16(a2[1][ks], bfrag, oacc[1][nt], 0, 0, 0);
      }
    }
    __syncthreads();
  }
  #pragma unroll
  for (int nt=0; nt<4; nt++){
    int col = wid*64 + nt*16 + li;
    float l2 = ls2[col];
    float cb = fc2_b[col];
    #pragma unroll
    for (int rt=0; rt<2; rt++){
      #pragma unroll
      for (int r=0; r<4; r++){
        int tok = tok0 + rt*16 + lg*4 + r;
        size_t p = (size_t)tok*256 + col;
        out[p] = xobuf[p] + l2*(oacc[rt][nt][r] + cb);
      }
    }
  }
}

extern "C" void kernel_launch(void* const* d_in, const int* in_sizes, int n_in,
                              void* d_out, int out_size, void* d_ws, size_t ws_size,
                              hipStream_t stream) {
  (void)in_sizes; (void)n_in; (void)out_size; (void)ws_size;
  const float* x      = (const float*)d_in[0];
  const float* y      = (const float*)d_in[1];
  const float* n1g    = (const float*)d_in[2];
  const float* n1b    = (const float*)d_in[3];
  const float* q_w    = (const float*)d_in[4];
  const float* kv_w   = (const float*)d_in[5];
  const float* proj_w = (const float*)d_in[6];
  const float* proj_b = (const float*)d_in[7];
  const float* n2g    = (const float*)d_in[8];
  const float* n2b    = (const float*)d_in[9];
  const float* fc1_w  = (const float*)d_in[10];
  const float* fc1_b  = (const float*)d_in[11];
  const float* fc2_w  = (const float*)d_in[12];
  const float* fc2_b  = (const float*)d_in[13];
  const float* ls1    = (const float*)d_in[14];
  const float* ls2    = (const float*)d_in[15];

  char* ws = (char*)d_ws;
  // Workspace (24.45 MB):
  //   qbuf  bf16[324*49*256]   @ 0          live K2..K3
  //   kbuf  bf16[2916*256]     @ 8,128,512  live K1..K3
  //   vbufT bf16[1024*736+512] @ 9,621,504  live K1..K3 (pads zeroed by K0)
  //   obuf  bf16[324*49*256]   @ 14,745,600 live K3..K4
  //   xobuf f32 [4*3600*256]   @ 0          live K4..K5 (overlays qbuf/kbuf/vbufT)
  //   W1F @22,874,112  W2F @23,398,400  PWF @23,922,688
  //   QWF @24,053,760  KVF @24,184,832  (ends 24,446,976)
  bf16*  qbuf  = (bf16*)(ws);
  bf16*  kbuf  = (bf16*)(ws + 8128512);
  bf16*  vbufT = (bf16*)(ws + 9621504);
  bf16*  obuf  = (bf16*)(ws + 14745600);
  float* xobuf = (float*)(ws);
  bf16*  W1F   = (bf16*)(ws + 22874112);
  bf16*  W2F   = (bf16*)(ws + 23398400);
  bf16*  PWF   = (bf16*)(ws + 23922688);
  bf16*  QWF   = (bf16*)(ws + 24053760);
  bf16*  KVF   = (bf16*)(ws + 24184832);

  wt_kernel<<<3102, 256, 0, stream>>>(fc1_w, fc2_w, proj_w, q_w, kv_w,
                                      W1F, W2F, PWF, QWF, KVF, vbufT);
  kv_kernel<<<183, 256, 0, stream>>>(y, n1g, n1b, KVF, kbuf, vbufT);
  q_kernel<<<324, 256, 0, stream>>>(x, n1g, n1b, QWF, qbuf);
  attn_kernel<<<2592, 256, 0, stream>>>(qbuf, kbuf, vbufT, obuf);
  proj_kernel<<<324, 256, 0, stream>>>(obuf, x, PWF, proj_b, ls1, xobuf);
  mlp_kernel<<<450, 256, 0, stream>>>(xobuf, n2g, n2b, W1F, fc1_b, W2F, fc2_b, ls2,
                                      (float*)d_out);
}